// Round 1
// baseline (1854.506 us; speedup 1.0000x reference)
//
#include <hip/hip_runtime.h>
#include <cstdint>
#include <cstddef>

// ---------------------------------------------------------------------------
// TreeModel: hierarchical bi-GRU (sentence-level + doc-level) + MLP head.
// Round 1: all-f32 correctness baseline with sane structure:
//   1) pack x-part weight columns -> packS [128,768], packD [256,1536]
//   2) embProj[V,768] = emb @ packS          (big GEMM, hoists x-projection)
//   3) sent_gru: 8 sentences/block, h-weights in VGPRs, 64-step loop in-block
//   4) xprojD[2048,1536] = sent @ packD
//   5) doc_gru: 4 docs/block, weights streamed from L2
//   6) mlp head -> logits [64,5]
// ---------------------------------------------------------------------------

__global__ void pack_cols(const float* __restrict__ src, float* __restrict__ dst,
                          int rows, int cols, int src_ld, int dst_ld, int coloff) {
  int i = blockIdx.x * 256 + threadIdx.x;
  if (i < rows * cols) {
    int r = i / cols, c = i - r * cols;
    dst[(size_t)r * dst_ld + coloff + c] = src[(size_t)r * src_ld + c];
  }
}

// C[M,N] = A[M,K] @ B[K,N];  N%64==0, K%16==0; M guarded. 256 thr, 64x64 tile.
__global__ __launch_bounds__(256) void gemm_f32(
    const float* __restrict__ A, const float* __restrict__ B, float* __restrict__ C,
    int M, int N, int K) {
  __shared__ float As[16][64];  // [k][m]
  __shared__ float Bs[16][64];  // [k][n]
  const int tid = threadIdx.x;
  const int bm = blockIdx.x * 64, bn = blockIdx.y * 64;
  const int tm = (tid >> 4) << 2, tn = (tid & 15) << 2;
  const int ar = tid >> 2, ac = (tid & 3) << 2;
  const int br = tid >> 4, bc = (tid & 15) << 2;
  float acc[4][4] = {};
  for (int k0 = 0; k0 < K; k0 += 16) {
    float4 av;
    if (bm + ar < M) av = *(const float4*)(A + (size_t)(bm + ar) * K + k0 + ac);
    else av = make_float4(0.f, 0.f, 0.f, 0.f);
    As[ac + 0][ar] = av.x; As[ac + 1][ar] = av.y;
    As[ac + 2][ar] = av.z; As[ac + 3][ar] = av.w;
    *(float4*)&Bs[br][bc] = *(const float4*)(B + (size_t)(k0 + br) * N + bn + bc);
    __syncthreads();
#pragma unroll
    for (int k = 0; k < 16; ++k) {
      float4 a = *(const float4*)&As[k][tm];
      float4 b = *(const float4*)&Bs[k][tn];
      acc[0][0] += a.x * b.x; acc[0][1] += a.x * b.y; acc[0][2] += a.x * b.z; acc[0][3] += a.x * b.w;
      acc[1][0] += a.y * b.x; acc[1][1] += a.y * b.y; acc[1][2] += a.y * b.z; acc[1][3] += a.y * b.w;
      acc[2][0] += a.z * b.x; acc[2][1] += a.z * b.y; acc[2][2] += a.z * b.z; acc[2][3] += a.z * b.w;
      acc[3][0] += a.w * b.x; acc[3][1] += a.w * b.y; acc[3][2] += a.w * b.z; acc[3][3] += a.w * b.w;
    }
    __syncthreads();
  }
#pragma unroll
  for (int i = 0; i < 4; ++i) {
    int row = bm + tm + i;
    if (row < M)
      *(float4*)(C + (size_t)row * N + bn + tn) =
          make_float4(acc[i][0], acc[i][1], acc[i][2], acc[i][3]);
  }
}

__device__ __forceinline__ float sigm(float x) { return 1.f / (1.f + __expf(-x)); }
__device__ __forceinline__ float tanh_fast(float x) {
  float e = __expf(2.f * x);
  return 1.f - 2.f / (e + 1.f);
}

// Sentence-level GRU. grid (256, 2=dir), block 256. 8 sentences per block.
// H=128. Gate cols j in [0,256): r=[0,128), u=[128,256). Cand cols: [0,128).
__global__ __launch_bounds__(256, 2) void sent_gru(
    const int* __restrict__ X, const int* __restrict__ L,
    const float* __restrict__ embProj,
    const float* __restrict__ Wg_f, const float* __restrict__ bgv_f,
    const float* __restrict__ Wc_f, const float* __restrict__ bcv_f,
    const float* __restrict__ Wg_b, const float* __restrict__ bgv_b,
    const float* __restrict__ Wc_b, const float* __restrict__ bcv_b,
    float* __restrict__ sent) {
  const int dir = blockIdx.y;
  const int g0 = blockIdx.x * 8;
  const int j = threadIdx.x;
  const float* Wg = dir ? Wg_b : Wg_f;
  const float* Wc = dir ? Wc_b : Wc_f;
  const float* bg = dir ? bgv_b : bgv_f;
  const float* bc = dir ? bcv_b : bcv_f;
  const int xg_off = dir ? 384 : 0;
  const int xc_off = dir ? 640 : 256;
  const int cj = j & 127;
  const int khalf = (j >> 7) << 6;  // 0 or 64

  __shared__ float h[8][128], rh[8][128], uu[8][128], part[8][128];
  __shared__ int wid[8];
  __shared__ int len_s[8];
  __shared__ int maxlen_s;

  // register-cached recurrent weights
  float wg[128];
  const float* Wg_h = Wg + 128 * 256;  // h-part rows of [256,256]
#pragma unroll
  for (int k = 0; k < 128; ++k) wg[k] = Wg_h[k * 256 + j];
  float wc[64];
  const float* Wc_h = Wc + 128 * 128;  // h-part rows of [256,128]
#pragma unroll
  for (int k = 0; k < 64; ++k) wc[k] = Wc_h[(khalf + k) * 128 + cj];
  const float bgj = bg[j];
  const float bcj = bc[cj];

  if (j < 8) len_s[j] = L[g0 + j];
  if (j < 128) {
#pragma unroll
    for (int m = 0; m < 8; ++m) h[m][j] = 0.f;
  }
  __syncthreads();
  if (j == 0) {
    int mx = 0;
#pragma unroll
    for (int m = 0; m < 8; ++m) mx = max(mx, len_s[m]);
    maxlen_s = mx;
  }
  __syncthreads();
  const int maxlen = maxlen_s;

  for (int t = 0; t < maxlen; ++t) {
    if (j < 8) {
      int l = len_s[j];
      int idx = dir ? (l - 1 - t) : t;
      wid[j] = (t < l) ? X[(g0 + j) * 64 + idx] : 0;
    }
    __syncthreads();
    float accs[8];
    // phase 1: gates (all 256 threads, one column each)
#pragma unroll
    for (int m = 0; m < 8; ++m) {
      if (t < len_s[m]) {
        float acc = bgj + embProj[(size_t)wid[m] * 768 + xg_off + j];
#pragma unroll
        for (int k = 0; k < 128; k += 4) {
          float4 hv = *(const float4*)&h[m][k];
          acc += hv.x * wg[k] + hv.y * wg[k + 1] + hv.z * wg[k + 2] + hv.w * wg[k + 3];
        }
        accs[m] = acc;
      }
    }
#pragma unroll
    for (int m = 0; m < 8; ++m) {
      if (t < len_s[m]) {
        float s = sigm(accs[m]);
        if (j < 128) rh[m][j] = s * h[m][j];   // r * h
        else uu[m][cj] = s;                    // u
      }
    }
    __syncthreads();
    // phase 2: candidate (128 cols x 2 k-halves over 256 threads)
#pragma unroll
    for (int m = 0; m < 8; ++m) {
      if (t < len_s[m]) {
        float acc = 0.f;
#pragma unroll
        for (int k = 0; k < 64; k += 4) {
          float4 rv = *(const float4*)&rh[m][khalf + k];
          acc += rv.x * wc[k] + rv.y * wc[k + 1] + rv.z * wc[k + 2] + rv.w * wc[k + 3];
        }
        accs[m] = acc;
      }
    }
    if (j >= 128) {
#pragma unroll
      for (int m = 0; m < 8; ++m)
        if (t < len_s[m]) part[m][cj] = accs[m];
    }
    __syncthreads();
    if (j < 128) {
#pragma unroll
      for (int m = 0; m < 8; ++m) {
        if (t < len_s[m]) {
          float pre = accs[m] + part[m][j] + bcj +
                      embProj[(size_t)wid[m] * 768 + xc_off + j];
          float c = tanh_fast(pre);
          float u = uu[m][j];
          h[m][j] = u * h[m][j] + (1.f - u) * c;
        }
      }
    }
    __syncthreads();
  }
  if (j < 128) {
#pragma unroll
    for (int m = 0; m < 8; ++m)
      sent[(size_t)(g0 + m) * 256 + dir * 128 + j] = h[m][j];
  }
}

// Doc-level GRU. grid (16, 2), block 512. 4 docs per block. H=256.
__global__ __launch_bounds__(512, 1) void doc_gru(
    const float* __restrict__ xprojD, const int* __restrict__ L2,
    const float* __restrict__ dWg_f, const float* __restrict__ dbg_f,
    const float* __restrict__ dWc_f, const float* __restrict__ dbc_f,
    const float* __restrict__ dWg_b, const float* __restrict__ dbg_b,
    const float* __restrict__ dWc_b, const float* __restrict__ dbc_b,
    float* __restrict__ docv) {
  const int dir = blockIdx.y;
  const int g0 = blockIdx.x * 4;
  const int j = threadIdx.x;  // 0..511
  const float* Wg_h = (dir ? dWg_b : dWg_f) + 256 * 512;
  const float* Wc_h = (dir ? dWc_b : dWc_f) + 256 * 256;
  const float* bg = dir ? dbg_b : dbg_f;
  const float* bc = dir ? dbc_b : dbc_f;
  const int xoff = dir ? 768 : 0;
  const int cj = j & 255;
  const int khalf = (j >> 8) << 7;  // 0 or 128

  __shared__ float h[4][256], rh[4][256], uu[4][256], part[4][256];
  __shared__ int len_s[4];

  if (j < 4) len_s[j] = L2[g0 + j];
  if (j < 256) {
#pragma unroll
    for (int m = 0; m < 4; ++m) h[m][j] = 0.f;
  }
  const float bgj = bg[j];
  const float bcj = bc[cj];
  __syncthreads();
  const int maxlen = max(max(len_s[0], len_s[1]), max(len_s[2], len_s[3]));

  for (int t = 0; t < maxlen; ++t) {
    float a[4];
#pragma unroll
    for (int m = 0; m < 4; ++m) {
      bool act = t < len_s[m];
      int ti = dir ? (len_s[m] - 1 - t) : t;
      a[m] = act ? bgj + xprojD[((size_t)(g0 + m) * 32 + ti) * 1536 + xoff + j] : 0.f;
    }
#pragma unroll 4
    for (int k = 0; k < 256; ++k) {
      float w = Wg_h[k * 512 + j];
#pragma unroll
      for (int m = 0; m < 4; ++m) a[m] += h[m][k] * w;
    }
#pragma unroll
    for (int m = 0; m < 4; ++m) {
      float s = sigm(a[m]);
      if (j < 256) rh[m][j] = s * h[m][j];
      else uu[m][cj] = s;
    }
    __syncthreads();
    float c[4] = {0.f, 0.f, 0.f, 0.f};
#pragma unroll 4
    for (int k = 0; k < 128; ++k) {
      float w = Wc_h[(khalf + k) * 256 + cj];
#pragma unroll
      for (int m = 0; m < 4; ++m) c[m] += rh[m][khalf + k] * w;
    }
    if (j >= 256) {
#pragma unroll
      for (int m = 0; m < 4; ++m) part[m][cj] = c[m];
    }
    __syncthreads();
    if (j < 256) {
#pragma unroll
      for (int m = 0; m < 4; ++m) {
        if (t < len_s[m]) {
          int ti = dir ? (len_s[m] - 1 - t) : t;
          float pre = c[m] + part[m][j] + bcj +
                      xprojD[((size_t)(g0 + m) * 32 + ti) * 1536 + xoff + 512 + j];
          float cn = tanh_fast(pre);
          float u = uu[m][j];
          h[m][j] = u * h[m][j] + (1.f - u) * cn;
        }
      }
    }
    __syncthreads();
  }
  if (j < 256) {
#pragma unroll
    for (int m = 0; m < 4; ++m)
      docv[(size_t)(g0 + m) * 512 + dir * 256 + j] = h[m][j];
  }
}

// MLP head: doc[64,512] -> relu(doc@W1+b1) -> @W2+b2 -> out[64,5]
__global__ __launch_bounds__(256) void mlp_head(
    const float* __restrict__ docv, const float* __restrict__ W1,
    const float* __restrict__ b1, const float* __restrict__ W2,
    const float* __restrict__ b2, float* __restrict__ out) {
  const int b = blockIdx.x, j = threadIdx.x;
  __shared__ float hid[256];
  float acc = b1[j];
#pragma unroll 4
  for (int k = 0; k < 512; ++k) acc += docv[b * 512 + k] * W1[k * 256 + j];
  hid[j] = fmaxf(acc, 0.f);
  __syncthreads();
  if (j < 5) {
    float a = b2[j];
#pragma unroll 4
    for (int k = 0; k < 256; ++k) a += hid[k] * W2[k * 5 + j];
    out[b * 5 + j] = a;
  }
}

extern "C" void kernel_launch(void* const* d_in, const int* in_sizes, int n_in,
                              void* d_out, int out_size, void* d_ws, size_t ws_size,
                              hipStream_t stream) {
  const int* X = (const int*)d_in[0];        // [64,32,64]
  const int* L = (const int*)d_in[1];        // [64,32]
  const int* L2 = (const int*)d_in[2];       // [64]
  const float* emb = (const float*)d_in[3];  // [50000,128]
  const float* sWg_f = (const float*)d_in[4];
  const float* sbg_f = (const float*)d_in[5];
  const float* sWc_f = (const float*)d_in[6];
  const float* sbc_f = (const float*)d_in[7];
  const float* sWg_b = (const float*)d_in[8];
  const float* sbg_b = (const float*)d_in[9];
  const float* sWc_b = (const float*)d_in[10];
  const float* sbc_b = (const float*)d_in[11];
  const float* dWg_f = (const float*)d_in[12];
  const float* dbg_f = (const float*)d_in[13];
  const float* dWc_f = (const float*)d_in[14];
  const float* dbc_f = (const float*)d_in[15];
  const float* dWg_b = (const float*)d_in[16];
  const float* dbg_b = (const float*)d_in[17];
  const float* dWc_b = (const float*)d_in[18];
  const float* dbc_b = (const float*)d_in[19];
  const float* W1 = (const float*)d_in[20];
  const float* b1 = (const float*)d_in[21];
  const float* W2 = (const float*)d_in[22];
  const float* b2 = (const float*)d_in[23];
  float* out = (float*)d_out;

  // workspace layout (floats)
  float* ws = (float*)d_ws;
  float* embProj = ws;                       // 50000*768
  float* sent = embProj + 38400000;          // 2048*256
  float* xprojD = sent + 524288;             // 2048*1536
  float* docv = xprojD + 3145728;            // 64*512
  float* packS = docv + 32768;               // 128*768
  float* packD = packS + 98304;              // 256*1536

  // 1) pack x-part weight columns
  auto packs = [&](const float* src, float* dst, int rows, int cols, int sld,
                   int dld, int off) {
    int n = rows * cols;
    hipLaunchKernelGGL(pack_cols, dim3((n + 255) / 256), dim3(256), 0, stream,
                       src, dst, rows, cols, sld, dld, off);
  };
  packs(sWg_f, packS, 128, 256, 256, 768, 0);
  packs(sWc_f, packS, 128, 128, 128, 768, 256);
  packs(sWg_b, packS, 128, 256, 256, 768, 384);
  packs(sWc_b, packS, 128, 128, 128, 768, 640);
  packs(dWg_f, packD, 256, 512, 512, 1536, 0);
  packs(dWc_f, packD, 256, 256, 256, 1536, 512);
  packs(dWg_b, packD, 256, 512, 512, 1536, 768);
  packs(dWc_b, packD, 256, 256, 256, 1536, 1280);

  // 2) embProj = emb @ packS   [50000,768]
  hipLaunchKernelGGL(gemm_f32, dim3(782, 12), dim3(256), 0, stream,
                     emb, packS, embProj, 50000, 768, 128);

  // 3) sentence bi-GRU -> sent [2048,256]
  hipLaunchKernelGGL(sent_gru, dim3(256, 2), dim3(256), 0, stream,
                     X, L, embProj,
                     sWg_f, sbg_f, sWc_f, sbc_f,
                     sWg_b, sbg_b, sWc_b, sbc_b, sent);

  // 4) xprojD = sent @ packD   [2048,1536]
  hipLaunchKernelGGL(gemm_f32, dim3(32, 24), dim3(256), 0, stream,
                     sent, packD, xprojD, 2048, 1536, 256);

  // 5) doc bi-GRU -> docv [64,512]
  hipLaunchKernelGGL(doc_gru, dim3(16, 2), dim3(512), 0, stream,
                     xprojD, L2,
                     dWg_f, dbg_f, dWc_f, dbc_f,
                     dWg_b, dbg_b, dWc_b, dbc_b, docv);

  // 6) MLP head -> out [64,5]
  hipLaunchKernelGGL(mlp_head, dim3(64), dim3(256), 0, stream,
                     docv, W1, b1, W2, b2, out);
}

// Round 2
// 1545.178 us; speedup vs baseline: 1.2002x; 1.2002x over previous
//
#include <hip/hip_runtime.h>
#include <cstdint>
#include <cstddef>

// ---------------------------------------------------------------------------
// TreeModel: hierarchical bi-GRU (sentence + doc) + MLP head. Round 2:
//   - gemm_f32 v2: 64x64 tile, K-stages of 128, padded LDS, grid (N/64, M/64)
//   - sent_gru v2: weights PINNED in VGPRs via asm, embProj x-vectors
//     prefetched one step ahead into LDS via global_load_lds (dbuf)
// ---------------------------------------------------------------------------

__global__ void pack_cols(const float* __restrict__ src, float* __restrict__ dst,
                          int rows, int cols, int src_ld, int dst_ld, int coloff) {
  int i = blockIdx.x * 256 + threadIdx.x;
  if (i < rows * cols) {
    int r = i / cols, c = i - r * cols;
    dst[(size_t)r * dst_ld + coloff + c] = src[(size_t)r * src_ld + c];
  }
}

// C[M,N] = A[M,K] @ B[K,N]; N%64==0, K%128==0; M guarded.
// grid (N/64, ceil(M/64)), block 256. 4x4 micro-tile.
__global__ __launch_bounds__(256) void gemm_f32(
    const float* __restrict__ A, const float* __restrict__ B, float* __restrict__ C,
    int M, int N, int K) {
  __shared__ float As[64][132];   // padded: kills 4-way bank conflict on A reads
  __shared__ float Bs[128][64];
  const int tid = threadIdx.x;
  const int bn = blockIdx.x * 64, bm = blockIdx.y * 64;
  const int tx = tid & 15, ty = tid >> 4;
  const int tm = ty * 4, tn = tx * 4;
  float acc[4][4] = {};
  for (int k0 = 0; k0 < K; k0 += 128) {
#pragma unroll
    for (int i = 0; i < 8; ++i) {           // A: 64 rows x 128 cols = 2048 f4
      int q = tid + 256 * i;
      int r = q >> 5, c4 = (q & 31) << 2;
      float4 v;
      if (bm + r < M) v = *(const float4*)(A + (size_t)(bm + r) * K + k0 + c4);
      else v = make_float4(0.f, 0.f, 0.f, 0.f);
      *(float4*)&As[r][c4] = v;
    }
#pragma unroll
    for (int i = 0; i < 8; ++i) {           // B: 128 rows x 64 cols = 2048 f4
      int q = tid + 256 * i;
      int r = q >> 4, c4 = (q & 15) << 2;
      *(float4*)&Bs[r][c4] = *(const float4*)(B + (size_t)(k0 + r) * N + bn + c4);
    }
    __syncthreads();
#pragma unroll
    for (int kq = 0; kq < 32; ++kq) {
      float4 av[4], bv[4];
#pragma unroll
      for (int i = 0; i < 4; ++i) av[i] = *(const float4*)&As[tm + i][kq * 4];
#pragma unroll
      for (int kk = 0; kk < 4; ++kk) bv[kk] = *(const float4*)&Bs[kq * 4 + kk][tn];
#pragma unroll
      for (int i = 0; i < 4; ++i) {
        const float* ap = (const float*)&av[i];
#pragma unroll
        for (int kk = 0; kk < 4; ++kk) {
          float a = ap[kk];
          const float* bp = (const float*)&bv[kk];
#pragma unroll
          for (int jj = 0; jj < 4; ++jj) acc[i][jj] += a * bp[jj];
        }
      }
    }
    __syncthreads();
  }
#pragma unroll
  for (int i = 0; i < 4; ++i) {
    int row = bm + tm + i;
    if (row < M)
      *(float4*)(C + (size_t)row * N + bn + tn) =
          make_float4(acc[i][0], acc[i][1], acc[i][2], acc[i][3]);
  }
}

__device__ __forceinline__ float sigm(float x) { return 1.f / (1.f + __expf(-x)); }
__device__ __forceinline__ float tanh_fast(float x) {
  float e = __expf(2.f * x);
  return 1.f - 2.f / (e + 1.f);
}

// Sentence-level GRU. grid (256, 2=dir), block 256. 8 sentences/block. H=128.
// Weights pinned in VGPRs; x-parts prefetched 1 step ahead into LDS dbuf.
__global__ __launch_bounds__(256, 2) void sent_gru(
    const int* __restrict__ X, const int* __restrict__ L,
    const float* __restrict__ embProj,
    const float* __restrict__ Wg_f, const float* __restrict__ bgv_f,
    const float* __restrict__ Wc_f, const float* __restrict__ bcv_f,
    const float* __restrict__ Wg_b, const float* __restrict__ bgv_b,
    const float* __restrict__ Wc_b, const float* __restrict__ bcv_b,
    float* __restrict__ sent) {
  const int dir = blockIdx.y;
  const int g0 = blockIdx.x * 8;
  const int j = threadIdx.x;
  const float* Wg = dir ? Wg_b : Wg_f;
  const float* Wc = dir ? Wc_b : Wc_f;
  const float* bg = dir ? bgv_b : bgv_f;
  const float* bc = dir ? bcv_b : bcv_f;
  const int cj = j & 127;
  const int khalf = (j >> 7) << 6;  // 0 or 64

  __shared__ float h[8][128], rh[8][128], uu[8][128], part[8][128];
  __shared__ float xbuf[2][8][384];   // per step: 384 f32 per sentence (gate 256 | cand 128)
  __shared__ int wid[2][8];
  __shared__ int len_s[8];

  // ---- load + PIN recurrent weights in registers ----
  float wg[128];
  const float* Wg_h = Wg + 128 * 256;
#pragma unroll
  for (int k = 0; k < 128; ++k) wg[k] = Wg_h[k * 256 + j];
  float wc[64];
  const float* Wc_h = Wc + 128 * 128;
#pragma unroll
  for (int k = 0; k < 64; ++k) wc[k] = Wc_h[(khalf + k) * 128 + cj];
#pragma unroll
  for (int k = 0; k < 128; ++k) asm volatile("" : "+v"(wg[k]));
#pragma unroll
  for (int k = 0; k < 64; ++k) asm volatile("" : "+v"(wc[k]));
  const float bgj = bg[j];
  const float bcj = bc[cj];

  if (j < 8) {
    int l = L[g0 + j];
    len_s[j] = l;
    wid[0][j] = X[(g0 + j) * 64 + (dir ? (l - 1) : 0)];
    wid[1][j] = (1 < l) ? X[(g0 + j) * 64 + (dir ? (l - 2) : 1)] : 0;
  }
  if (j < 128) {
#pragma unroll
    for (int m = 0; m < 8; ++m) h[m][j] = 0.f;
  }
  __syncthreads();

  // prefetch x(t) into xbuf[t&1]; wid[t&1] must be valid
  auto prefetch_x = [&](int t) {
    int b = t & 1;
#pragma unroll
    for (int c = 0; c < 3; ++c) {
      int q = j + 256 * c;        // f4 index in [0,768)
      int m = q / 96;
      int s = q - m * 96;
      const float* src = embProj + (size_t)wid[b][m] * 768 + dir * 384 + s * 4;
      float* dst = (float*)&xbuf[b][0][0] + q * 4;
      __builtin_amdgcn_global_load_lds(
          (const __attribute__((address_space(1))) void*)src,
          (__attribute__((address_space(3))) void*)dst, 16, 0, 0);
    }
  };

  prefetch_x(0);
  int maxlen = 0;
#pragma unroll
  for (int m = 0; m < 8; ++m) maxlen = max(maxlen, len_s[m]);
  __syncthreads();   // drains vmcnt: xbuf[0] ready

  for (int t = 0; t < maxlen; ++t) {
    const int cur = t & 1;
    // phase 0: issue gathers for t+1; load word-ids for t+2
    prefetch_x(t + 1);
    if (j < 8) {
      int l = len_s[j];
      int tt = t + 2;
      wid[tt & 1][j] = (tt < l) ? X[(g0 + j) * 64 + (dir ? (l - 1 - tt) : tt)] : 0;
    }
    // phase 1: gates (256 cols, full K=128 per thread)
    float accs[8];
#pragma unroll
    for (int m = 0; m < 8; ++m) {
      if (t < len_s[m]) {
        float acc = bgj + xbuf[cur][m][j];
#pragma unroll
        for (int k = 0; k < 128; k += 4) {
          float4 hv = *(const float4*)&h[m][k];
          acc += hv.x * wg[k] + hv.y * wg[k + 1] + hv.z * wg[k + 2] + hv.w * wg[k + 3];
        }
        accs[m] = acc;
      }
    }
#pragma unroll
    for (int m = 0; m < 8; ++m) {
      if (t < len_s[m]) {
        float s = sigm(accs[m]);
        if (j < 128) rh[m][j] = s * h[m][j];
        else uu[m][cj] = s;
      }
    }
    __syncthreads();   // A: rh/uu visible; prefetch loads drained
    // phase 2: candidate partials (128 cols x 2 k-halves)
#pragma unroll
    for (int m = 0; m < 8; ++m) {
      if (t < len_s[m]) {
        float acc = 0.f;
#pragma unroll
        for (int k = 0; k < 64; k += 4) {
          float4 rv = *(const float4*)&rh[m][khalf + k];
          acc += rv.x * wc[k] + rv.y * wc[k + 1] + rv.z * wc[k + 2] + rv.w * wc[k + 3];
        }
        accs[m] = acc;
      }
    }
    if (j >= 128) {
#pragma unroll
      for (int m = 0; m < 8; ++m)
        if (t < len_s[m]) part[m][cj] = accs[m];
    }
    __syncthreads();   // B: partials visible
    // phase 3: finalize candidate + h update (128 cols)
    if (j < 128) {
#pragma unroll
      for (int m = 0; m < 8; ++m) {
        if (t < len_s[m]) {
          float pre = accs[m] + part[m][j] + bcj + xbuf[cur][m][256 + j];
          float c = tanh_fast(pre);
          float u = uu[m][j];
          h[m][j] = u * h[m][j] + (1.f - u) * c;
        }
      }
    }
    __syncthreads();   // C: h visible for next step
  }
  if (j < 128) {
#pragma unroll
    for (int m = 0; m < 8; ++m)
      sent[(size_t)(g0 + m) * 256 + dir * 128 + j] = h[m][j];
  }
}

// Doc-level GRU. grid (16, 2), block 512. 4 docs per block. H=256.
__global__ __launch_bounds__(512, 1) void doc_gru(
    const float* __restrict__ xprojD, const int* __restrict__ L2,
    const float* __restrict__ dWg_f, const float* __restrict__ dbg_f,
    const float* __restrict__ dWc_f, const float* __restrict__ dbc_f,
    const float* __restrict__ dWg_b, const float* __restrict__ dbg_b,
    const float* __restrict__ dWc_b, const float* __restrict__ dbc_b,
    float* __restrict__ docv) {
  const int dir = blockIdx.y;
  const int g0 = blockIdx.x * 4;
  const int j = threadIdx.x;
  const float* Wg_h = (dir ? dWg_b : dWg_f) + 256 * 512;
  const float* Wc_h = (dir ? dWc_b : dWc_f) + 256 * 256;
  const float* bg = dir ? dbg_b : dbg_f;
  const float* bc = dir ? dbc_b : dbc_f;
  const int xoff = dir ? 768 : 0;
  const int cj = j & 255;
  const int khalf = (j >> 8) << 7;

  __shared__ float h[4][256], rh[4][256], uu[4][256], part[4][256];
  __shared__ int len_s[4];

  if (j < 4) len_s[j] = L2[g0 + j];
  if (j < 256) {
#pragma unroll
    for (int m = 0; m < 4; ++m) h[m][j] = 0.f;
  }
  const float bgj = bg[j];
  const float bcj = bc[cj];
  __syncthreads();
  const int maxlen = max(max(len_s[0], len_s[1]), max(len_s[2], len_s[3]));

  for (int t = 0; t < maxlen; ++t) {
    float a[4];
#pragma unroll
    for (int m = 0; m < 4; ++m) {
      bool act = t < len_s[m];
      int ti = dir ? (len_s[m] - 1 - t) : t;
      a[m] = act ? bgj + xprojD[((size_t)(g0 + m) * 32 + ti) * 1536 + xoff + j] : 0.f;
    }
#pragma unroll 4
    for (int k = 0; k < 256; ++k) {
      float w = Wg_h[k * 512 + j];
#pragma unroll
      for (int m = 0; m < 4; ++m) a[m] += h[m][k] * w;
    }
#pragma unroll
    for (int m = 0; m < 4; ++m) {
      float s = sigm(a[m]);
      if (j < 256) rh[m][j] = s * h[m][j];
      else uu[m][cj] = s;
    }
    __syncthreads();
    float c[4] = {0.f, 0.f, 0.f, 0.f};
#pragma unroll 4
    for (int k = 0; k < 128; ++k) {
      float w = Wc_h[(khalf + k) * 256 + cj];
#pragma unroll
      for (int m = 0; m < 4; ++m) c[m] += rh[m][khalf + k] * w;
    }
    if (j >= 256) {
#pragma unroll
      for (int m = 0; m < 4; ++m) part[m][cj] = c[m];
    }
    __syncthreads();
    if (j < 256) {
#pragma unroll
      for (int m = 0; m < 4; ++m) {
        if (t < len_s[m]) {
          int ti = dir ? (len_s[m] - 1 - t) : t;
          float pre = c[m] + part[m][j] + bcj +
                      xprojD[((size_t)(g0 + m) * 32 + ti) * 1536 + xoff + 512 + j];
          float cn = tanh_fast(pre);
          float u = uu[m][j];
          h[m][j] = u * h[m][j] + (1.f - u) * cn;
        }
      }
    }
    __syncthreads();
  }
  if (j < 256) {
#pragma unroll
    for (int m = 0; m < 4; ++m)
      docv[(size_t)(g0 + m) * 512 + dir * 256 + j] = h[m][j];
  }
}

__global__ __launch_bounds__(256) void mlp_head(
    const float* __restrict__ docv, const float* __restrict__ W1,
    const float* __restrict__ b1, const float* __restrict__ W2,
    const float* __restrict__ b2, float* __restrict__ out) {
  const int b = blockIdx.x, j = threadIdx.x;
  __shared__ float hid[256];
  float acc = b1[j];
#pragma unroll 4
  for (int k = 0; k < 512; ++k) acc += docv[b * 512 + k] * W1[k * 256 + j];
  hid[j] = fmaxf(acc, 0.f);
  __syncthreads();
  if (j < 5) {
    float a = b2[j];
#pragma unroll 4
    for (int k = 0; k < 256; ++k) a += hid[k] * W2[k * 5 + j];
    out[b * 5 + j] = a;
  }
}

extern "C" void kernel_launch(void* const* d_in, const int* in_sizes, int n_in,
                              void* d_out, int out_size, void* d_ws, size_t ws_size,
                              hipStream_t stream) {
  const int* X = (const int*)d_in[0];
  const int* L = (const int*)d_in[1];
  const int* L2 = (const int*)d_in[2];
  const float* emb = (const float*)d_in[3];
  const float* sWg_f = (const float*)d_in[4];
  const float* sbg_f = (const float*)d_in[5];
  const float* sWc_f = (const float*)d_in[6];
  const float* sbc_f = (const float*)d_in[7];
  const float* sWg_b = (const float*)d_in[8];
  const float* sbg_b = (const float*)d_in[9];
  const float* sWc_b = (const float*)d_in[10];
  const float* sbc_b = (const float*)d_in[11];
  const float* dWg_f = (const float*)d_in[12];
  const float* dbg_f = (const float*)d_in[13];
  const float* dWc_f = (const float*)d_in[14];
  const float* dbc_f = (const float*)d_in[15];
  const float* dWg_b = (const float*)d_in[16];
  const float* dbg_b = (const float*)d_in[17];
  const float* dWc_b = (const float*)d_in[18];
  const float* dbc_b = (const float*)d_in[19];
  const float* W1 = (const float*)d_in[20];
  const float* b1 = (const float*)d_in[21];
  const float* W2 = (const float*)d_in[22];
  const float* b2 = (const float*)d_in[23];
  float* out = (float*)d_out;

  float* ws = (float*)d_ws;
  float* embProj = ws;                       // 50000*768
  float* sent = embProj + 38400000;          // 2048*256
  float* xprojD = sent + 524288;             // 2048*1536
  float* docv = xprojD + 3145728;            // 64*512
  float* packS = docv + 32768;               // 128*768
  float* packD = packS + 98304;              // 256*1536

  auto packs = [&](const float* src, float* dst, int rows, int cols, int sld,
                   int dld, int off) {
    int n = rows * cols;
    hipLaunchKernelGGL(pack_cols, dim3((n + 255) / 256), dim3(256), 0, stream,
                       src, dst, rows, cols, sld, dld, off);
  };
  packs(sWg_f, packS, 128, 256, 256, 768, 0);
  packs(sWc_f, packS, 128, 128, 128, 768, 256);
  packs(sWg_b, packS, 128, 256, 256, 768, 384);
  packs(sWc_b, packS, 128, 128, 128, 768, 640);
  packs(dWg_f, packD, 256, 512, 512, 1536, 0);
  packs(dWc_f, packD, 256, 256, 256, 1536, 512);
  packs(dWg_b, packD, 256, 512, 512, 1536, 768);
  packs(dWc_b, packD, 256, 256, 256, 1536, 1280);

  // embProj = emb @ packS  [50000,768]; grid (N/64, M/64): N-blocks adjacent
  hipLaunchKernelGGL(gemm_f32, dim3(12, 782), dim3(256), 0, stream,
                     emb, packS, embProj, 50000, 768, 128);

  hipLaunchKernelGGL(sent_gru, dim3(256, 2), dim3(256), 0, stream,
                     X, L, embProj,
                     sWg_f, sbg_f, sWc_f, sbc_f,
                     sWg_b, sbg_b, sWc_b, sbc_b, sent);

  // xprojD = sent @ packD  [2048,1536], K=256
  hipLaunchKernelGGL(gemm_f32, dim3(24, 32), dim3(256), 0, stream,
                     sent, packD, xprojD, 2048, 1536, 256);

  hipLaunchKernelGGL(doc_gru, dim3(16, 2), dim3(512), 0, stream,
                     xprojD, L2,
                     dWg_f, dbg_f, dWc_f, dbc_f,
                     dWg_b, dbg_b, dWc_b, dbc_b, docv);

  hipLaunchKernelGGL(mlp_head, dim3(64), dim3(256), 0, stream,
                     docv, W1, b1, W2, b2, out);
}

// Round 3
// 1103.453 us; speedup vs baseline: 1.6806x; 1.4003x over previous
//
#include <hip/hip_runtime.h>
#include <cstdint>
#include <cstddef>

// ---------------------------------------------------------------------------
// TreeModel: hierarchical bi-GRU (sentence + doc) + MLP head. Round 3:
//   - sent_gru v3: MFMA 16x16x32 bf16 with split-bf16 (hi/lo, 3 passes)
//     16 sentences/block, weights as bf16 frags in VGPRs, h in LDS
//   - everything else unchanged from round 2
// ---------------------------------------------------------------------------

typedef __attribute__((ext_vector_type(8))) short bf16x8;   // 8 bf16 = 4 VGPR
typedef __attribute__((ext_vector_type(4))) float f32x4;    // C/D frag

__device__ __forceinline__ void split_bf16(float f, short& hi, short& lo) {
  unsigned u = __float_as_uint(f);
  unsigned rb = (u + 0x7FFFu + ((u >> 16) & 1u)) & 0xFFFF0000u;  // RNE
  hi = (short)(rb >> 16);
  float r = f - __uint_as_float(rb);
  unsigned ur = __float_as_uint(r);
  lo = (short)((ur + 0x7FFFu + ((ur >> 16) & 1u)) >> 16);
}

__global__ void pack_cols(const float* __restrict__ src, float* __restrict__ dst,
                          int rows, int cols, int src_ld, int dst_ld, int coloff) {
  int i = blockIdx.x * 256 + threadIdx.x;
  if (i < rows * cols) {
    int r = i / cols, c = i - r * cols;
    dst[(size_t)r * dst_ld + coloff + c] = src[(size_t)r * src_ld + c];
  }
}

// C[M,N] = A[M,K] @ B[K,N]; N%64==0, K%128==0; M guarded.
__global__ __launch_bounds__(256) void gemm_f32(
    const float* __restrict__ A, const float* __restrict__ B, float* __restrict__ C,
    int M, int N, int K) {
  __shared__ float As[64][132];
  __shared__ float Bs[128][64];
  const int tid = threadIdx.x;
  const int bn = blockIdx.x * 64, bm = blockIdx.y * 64;
  const int tx = tid & 15, ty = tid >> 4;
  const int tm = ty * 4, tn = tx * 4;
  float acc[4][4] = {};
  for (int k0 = 0; k0 < K; k0 += 128) {
#pragma unroll
    for (int i = 0; i < 8; ++i) {
      int q = tid + 256 * i;
      int r = q >> 5, c4 = (q & 31) << 2;
      float4 v;
      if (bm + r < M) v = *(const float4*)(A + (size_t)(bm + r) * K + k0 + c4);
      else v = make_float4(0.f, 0.f, 0.f, 0.f);
      *(float4*)&As[r][c4] = v;
    }
#pragma unroll
    for (int i = 0; i < 8; ++i) {
      int q = tid + 256 * i;
      int r = q >> 4, c4 = (q & 15) << 2;
      *(float4*)&Bs[r][c4] = *(const float4*)(B + (size_t)(k0 + r) * N + bn + c4);
    }
    __syncthreads();
#pragma unroll
    for (int kq = 0; kq < 32; ++kq) {
      float4 av[4], bv[4];
#pragma unroll
      for (int i = 0; i < 4; ++i) av[i] = *(const float4*)&As[tm + i][kq * 4];
#pragma unroll
      for (int kk = 0; kk < 4; ++kk) bv[kk] = *(const float4*)&Bs[kq * 4 + kk][tn];
#pragma unroll
      for (int i = 0; i < 4; ++i) {
        const float* ap = (const float*)&av[i];
#pragma unroll
        for (int kk = 0; kk < 4; ++kk) {
          float a = ap[kk];
          const float* bp = (const float*)&bv[kk];
#pragma unroll
          for (int jj = 0; jj < 4; ++jj) acc[i][jj] += a * bp[jj];
        }
      }
    }
    __syncthreads();
  }
#pragma unroll
  for (int i = 0; i < 4; ++i) {
    int row = bm + tm + i;
    if (row < M)
      *(float4*)(C + (size_t)row * N + bn + tn) =
          make_float4(acc[i][0], acc[i][1], acc[i][2], acc[i][3]);
  }
}

__device__ __forceinline__ float sigm(float x) { return 1.f / (1.f + __expf(-x)); }
__device__ __forceinline__ float tanh_fast(float x) {
  float e = __expf(2.f * x);
  return 1.f - 2.f / (e + 1.f);
}

// ---------------------------------------------------------------------------
// Sentence GRU, MFMA version. grid (128, 2=dir), block 256 (4 waves).
// 16 sentences/block. H=128. Gate cols: wave w owns [64w,64w+64) (4 N-tiles);
// cand cols: wave w owns [32w,32w+32) (2 N-tiles).
// MFMA 16x16x32 bf16: A lane l: row=l&15, k=8*(l>>4)+e (+32*kk)
//                     B lane l: col=l&15, k=8*(l>>4)+e
//                     C lane l: col=l&15, row=4*(l>>4)+r
// ---------------------------------------------------------------------------
#define SENTS 16

__global__ __launch_bounds__(256, 1) void sent_gru(
    const int* __restrict__ X, const int* __restrict__ L,
    const float* __restrict__ embProj,
    const float* __restrict__ Wg_f, const float* __restrict__ bg_f,
    const float* __restrict__ Wc_f, const float* __restrict__ bc_f,
    const float* __restrict__ Wg_b, const float* __restrict__ bg_b,
    const float* __restrict__ Wc_b, const float* __restrict__ bc_b,
    float* __restrict__ sent) {
  const int dir = blockIdx.y;
  const int g0 = blockIdx.x * SENTS;
  const int tid = threadIdx.x;
  const int w = tid >> 6, l = tid & 63;
  const int li = l & 15, g = l >> 4;
  const float* Wg = dir ? Wg_b : Wg_f;
  const float* Wc = dir ? Wc_b : Wc_f;
  const float* bgp = dir ? bg_b : bg_f;
  const float* bcp = dir ? bc_b : bc_f;

  __shared__ float xbuf[2][SENTS][384];                 // [gate 256 | cand 128]
  __shared__ float h_f[SENTS][132];
  __shared__ float u_f[SENTS][132];
  alignas(16) __shared__ short h_hi[SENTS][136], h_lo[SENTS][136];
  alignas(16) __shared__ short rh_hi[SENTS][136], rh_lo[SENTS][136];
  __shared__ int wid[2][SENTS];
  __shared__ int len_s[SENTS];

  // ---- one-time: load + split recurrent weights into bf16 B-fragments ----
  bf16x8 bg_hi[4][4], bg_lo[4][4];     // gates: [nt][kk]
  bf16x8 bc_hi[2][4], bc_lo[2][4];     // cand:  [ct][kk]
#pragma unroll
  for (int nt = 0; nt < 4; ++nt)
#pragma unroll
    for (int kk = 0; kk < 4; ++kk) {
      const float* base = Wg + (size_t)(128 + 32 * kk + 8 * g) * 256 + 64 * w + 16 * nt + li;
#pragma unroll
      for (int e = 0; e < 8; ++e) {
        short hi, lo;
        split_bf16(base[(size_t)e * 256], hi, lo);
        bg_hi[nt][kk][e] = hi; bg_lo[nt][kk][e] = lo;
      }
    }
#pragma unroll
  for (int ct = 0; ct < 2; ++ct)
#pragma unroll
    for (int kk = 0; kk < 4; ++kk) {
      const float* base = Wc + (size_t)(128 + 32 * kk + 8 * g) * 128 + 32 * w + 16 * ct + li;
#pragma unroll
      for (int e = 0; e < 8; ++e) {
        short hi, lo;
        split_bf16(base[(size_t)e * 128], hi, lo);
        bc_hi[ct][kk][e] = hi; bc_lo[ct][kk][e] = lo;
      }
    }
  float bgj[4], bcj[2];
#pragma unroll
  for (int nt = 0; nt < 4; ++nt) bgj[nt] = bgp[64 * w + 16 * nt + li];
#pragma unroll
  for (int ct = 0; ct < 2; ++ct) bcj[ct] = bcp[32 * w + 16 * ct + li];

  if (tid < SENTS) {
    int ll = L[g0 + tid];
    len_s[tid] = ll;
    wid[0][tid] = X[(g0 + tid) * 64 + (dir ? (ll - 1) : 0)];
    wid[1][tid] = (1 < ll) ? X[(g0 + tid) * 64 + (dir ? (ll - 2) : 1)] : 0;
  }
  for (int q = tid; q < SENTS * 136; q += 256) {
    ((short*)h_hi)[q] = 0; ((short*)h_lo)[q] = 0;
  }
  for (int q = tid; q < SENTS * 132; q += 256) ((float*)h_f)[q] = 0.f;
  __syncthreads();

  int lens4[4];
#pragma unroll
  for (int r = 0; r < 4; ++r) lens4[r] = len_s[4 * g + r];
  int maxlen = 0;
#pragma unroll
  for (int m = 0; m < SENTS; ++m) maxlen = max(maxlen, len_s[m]);

  // prefetch x(t) into xbuf[t&1] via global_load_lds (lane-linear dest)
  auto prefetch_x = [&](int t) {
    int b = t & 1;
#pragma unroll
    for (int c = 0; c < 6; ++c) {
      int q = tid + 256 * c;                 // f4 index in [0,1536)
      int m = q / 96, s = q - m * 96;
      const float* src = embProj + (size_t)wid[b][m] * 768 + dir * 384 + s * 4;
      float* dst = (float*)&xbuf[b][0][0] + q * 4;
      __builtin_amdgcn_global_load_lds(
          (const __attribute__((address_space(1))) void*)src,
          (__attribute__((address_space(3))) void*)dst, 16, 0, 0);
    }
  };

  prefetch_x(0);
  __syncthreads();   // drains vmcnt -> xbuf[0] ready

  for (int t = 0; t < maxlen; ++t) {
    const int cur = t & 1;
    prefetch_x(t + 1);
    if (tid < SENTS) {
      int ll = len_s[tid], tt = t + 2;
      wid[tt & 1][tid] = (tt < ll) ? X[(g0 + tid) * 64 + (dir ? (ll - 1 - tt) : tt)] : 0;
    }

    // ---- P1: gates = H @ Wg_h (+x+b), sigmoid, write rh / u ----
    bf16x8 a_hi[4], a_lo[4];
#pragma unroll
    for (int kk = 0; kk < 4; ++kk) {
      a_hi[kk] = *(const bf16x8*)&h_hi[li][32 * kk + 8 * g];
      a_lo[kk] = *(const bf16x8*)&h_lo[li][32 * kk + 8 * g];
    }
    f32x4 accg[4];
#pragma unroll
    for (int nt = 0; nt < 4; ++nt) {
      const int col = 64 * w + 16 * nt + li;
      f32x4 c;
#pragma unroll
      for (int r = 0; r < 4; ++r) c[r] = bgj[nt] + xbuf[cur][4 * g + r][col];
#pragma unroll
      for (int kk = 0; kk < 4; ++kk) {
        c = __builtin_amdgcn_mfma_f32_16x16x32_bf16(a_hi[kk], bg_hi[nt][kk], c, 0, 0, 0);
        c = __builtin_amdgcn_mfma_f32_16x16x32_bf16(a_hi[kk], bg_lo[nt][kk], c, 0, 0, 0);
        c = __builtin_amdgcn_mfma_f32_16x16x32_bf16(a_lo[kk], bg_hi[nt][kk], c, 0, 0, 0);
      }
      accg[nt] = c;
    }
    if (w < 2) {                 // r-columns: rh = sigmoid * h, split to bf16
#pragma unroll
      for (int nt = 0; nt < 4; ++nt) {
        const int col = 64 * w + 16 * nt + li;
#pragma unroll
        for (int r = 0; r < 4; ++r) {
          const int row = 4 * g + r;
          float s = sigm(accg[nt][r]);
          float rh = s * h_f[row][col];
          short hi, lo;
          split_bf16(rh, hi, lo);
          rh_hi[row][col] = hi;
          rh_lo[row][col] = lo;
        }
      }
    } else {                     // u-columns
#pragma unroll
      for (int nt = 0; nt < 4; ++nt) {
        const int col = 64 * (w - 2) + 16 * nt + li;
#pragma unroll
        for (int r = 0; r < 4; ++r) {
          u_f[4 * g + r][col] = sigm(accg[nt][r]);
        }
      }
    }
    __syncthreads();   // rh/u visible; prefetch drained

    // ---- P2: cand = RH @ Wc_h (+x+b), tanh, masked h update ----
    bf16x8 ra_hi[4], ra_lo[4];
#pragma unroll
    for (int kk = 0; kk < 4; ++kk) {
      ra_hi[kk] = *(const bf16x8*)&rh_hi[li][32 * kk + 8 * g];
      ra_lo[kk] = *(const bf16x8*)&rh_lo[li][32 * kk + 8 * g];
    }
#pragma unroll
    for (int ct = 0; ct < 2; ++ct) {
      const int col = 32 * w + 16 * ct + li;
      f32x4 c;
#pragma unroll
      for (int r = 0; r < 4; ++r) c[r] = bcj[ct] + xbuf[cur][4 * g + r][256 + col];
#pragma unroll
      for (int kk = 0; kk < 4; ++kk) {
        c = __builtin_amdgcn_mfma_f32_16x16x32_bf16(ra_hi[kk], bc_hi[ct][kk], c, 0, 0, 0);
        c = __builtin_amdgcn_mfma_f32_16x16x32_bf16(ra_hi[kk], bc_lo[ct][kk], c, 0, 0, 0);
        c = __builtin_amdgcn_mfma_f32_16x16x32_bf16(ra_lo[kk], bc_hi[ct][kk], c, 0, 0, 0);
      }
#pragma unroll
      for (int r = 0; r < 4; ++r) {
        const int row = 4 * g + r;
        float cand = tanh_fast(c[r]);
        float u = u_f[row][col];
        float hold = h_f[row][col];
        float hn = u * hold + (1.f - u) * cand;
        hn = (t < lens4[r]) ? hn : hold;
        h_f[row][col] = hn;
        short hi, lo;
        split_bf16(hn, hi, lo);
        h_hi[row][col] = hi;
        h_lo[row][col] = lo;
      }
    }
    __syncthreads();   // h planes ready for next step
  }

  for (int q = tid; q < SENTS * 128; q += 256) {
    int m = q >> 7, j = q & 127;
    sent[(size_t)(g0 + m) * 256 + dir * 128 + j] = h_f[m][j];
  }
}

// Doc-level GRU. grid (16, 2), block 512. 4 docs per block. H=256.
__global__ __launch_bounds__(512, 1) void doc_gru(
    const float* __restrict__ xprojD, const int* __restrict__ L2,
    const float* __restrict__ dWg_f, const float* __restrict__ dbg_f,
    const float* __restrict__ dWc_f, const float* __restrict__ dbc_f,
    const float* __restrict__ dWg_b, const float* __restrict__ dbg_b,
    const float* __restrict__ dWc_b, const float* __restrict__ dbc_b,
    float* __restrict__ docv) {
  const int dir = blockIdx.y;
  const int g0 = blockIdx.x * 4;
  const int j = threadIdx.x;
  const float* Wg_h = (dir ? dWg_b : dWg_f) + 256 * 512;
  const float* Wc_h = (dir ? dWc_b : dWc_f) + 256 * 256;
  const float* bg = dir ? dbg_b : dbg_f;
  const float* bc = dir ? dbc_b : dbc_f;
  const int xoff = dir ? 768 : 0;
  const int cj = j & 255;
  const int khalf = (j >> 8) << 7;

  __shared__ float h[4][256], rh[4][256], uu[4][256], part[4][256];
  __shared__ int len_s[4];

  if (j < 4) len_s[j] = L2[g0 + j];
  if (j < 256) {
#pragma unroll
    for (int m = 0; m < 4; ++m) h[m][j] = 0.f;
  }
  const float bgj = bg[j];
  const float bcj = bc[cj];
  __syncthreads();
  const int maxlen = max(max(len_s[0], len_s[1]), max(len_s[2], len_s[3]));

  for (int t = 0; t < maxlen; ++t) {
    float a[4];
#pragma unroll
    for (int m = 0; m < 4; ++m) {
      bool act = t < len_s[m];
      int ti = dir ? (len_s[m] - 1 - t) : t;
      a[m] = act ? bgj + xprojD[((size_t)(g0 + m) * 32 + ti) * 1536 + xoff + j] : 0.f;
    }
#pragma unroll 4
    for (int k = 0; k < 256; ++k) {
      float wv = Wg_h[k * 512 + j];
#pragma unroll
      for (int m = 0; m < 4; ++m) a[m] += h[m][k] * wv;
    }
#pragma unroll
    for (int m = 0; m < 4; ++m) {
      float s = sigm(a[m]);
      if (j < 256) rh[m][j] = s * h[m][j];
      else uu[m][cj] = s;
    }
    __syncthreads();
    float c[4] = {0.f, 0.f, 0.f, 0.f};
#pragma unroll 4
    for (int k = 0; k < 128; ++k) {
      float wv = Wc_h[(khalf + k) * 256 + cj];
#pragma unroll
      for (int m = 0; m < 4; ++m) c[m] += rh[m][khalf + k] * wv;
    }
    if (j >= 256) {
#pragma unroll
      for (int m = 0; m < 4; ++m) part[m][cj] = c[m];
    }
    __syncthreads();
    if (j < 256) {
#pragma unroll
      for (int m = 0; m < 4; ++m) {
        if (t < len_s[m]) {
          int ti = dir ? (len_s[m] - 1 - t) : t;
          float pre = c[m] + part[m][j] + bcj +
                      xprojD[((size_t)(g0 + m) * 32 + ti) * 1536 + xoff + 512 + j];
          float cn = tanh_fast(pre);
          float u = uu[m][j];
          h[m][j] = u * h[m][j] + (1.f - u) * cn;
        }
      }
    }
    __syncthreads();
  }
  if (j < 256) {
#pragma unroll
    for (int m = 0; m < 4; ++m)
      docv[(size_t)(g0 + m) * 512 + dir * 256 + j] = h[m][j];
  }
}

__global__ __launch_bounds__(256) void mlp_head(
    const float* __restrict__ docv, const float* __restrict__ W1,
    const float* __restrict__ b1, const float* __restrict__ W2,
    const float* __restrict__ b2, float* __restrict__ out) {
  const int b = blockIdx.x, j = threadIdx.x;
  __shared__ float hid[256];
  float acc = b1[j];
#pragma unroll 4
  for (int k = 0; k < 512; ++k) acc += docv[b * 512 + k] * W1[k * 256 + j];
  hid[j] = fmaxf(acc, 0.f);
  __syncthreads();
  if (j < 5) {
    float a = b2[j];
#pragma unroll 4
    for (int k = 0; k < 256; ++k) a += hid[k] * W2[k * 5 + j];
    out[b * 5 + j] = a;
  }
}

extern "C" void kernel_launch(void* const* d_in, const int* in_sizes, int n_in,
                              void* d_out, int out_size, void* d_ws, size_t ws_size,
                              hipStream_t stream) {
  const int* X = (const int*)d_in[0];
  const int* L = (const int*)d_in[1];
  const int* L2 = (const int*)d_in[2];
  const float* emb = (const float*)d_in[3];
  const float* sWg_f = (const float*)d_in[4];
  const float* sbg_f = (const float*)d_in[5];
  const float* sWc_f = (const float*)d_in[6];
  const float* sbc_f = (const float*)d_in[7];
  const float* sWg_b = (const float*)d_in[8];
  const float* sbg_b = (const float*)d_in[9];
  const float* sWc_b = (const float*)d_in[10];
  const float* sbc_b = (const float*)d_in[11];
  const float* dWg_f = (const float*)d_in[12];
  const float* dbg_f = (const float*)d_in[13];
  const float* dWc_f = (const float*)d_in[14];
  const float* dbc_f = (const float*)d_in[15];
  const float* dWg_b = (const float*)d_in[16];
  const float* dbg_b = (const float*)d_in[17];
  const float* dWc_b = (const float*)d_in[18];
  const float* dbc_b = (const float*)d_in[19];
  const float* W1 = (const float*)d_in[20];
  const float* b1 = (const float*)d_in[21];
  const float* W2 = (const float*)d_in[22];
  const float* b2 = (const float*)d_in[23];
  float* out = (float*)d_out;

  float* ws = (float*)d_ws;
  float* embProj = ws;                       // 50000*768
  float* sent = embProj + 38400000;          // 2048*256
  float* xprojD = sent + 524288;             // 2048*1536
  float* docv = xprojD + 3145728;            // 64*512
  float* packS = docv + 32768;               // 128*768
  float* packD = packS + 98304;              // 256*1536

  auto packs = [&](const float* src, float* dst, int rows, int cols, int sld,
                   int dld, int off) {
    int n = rows * cols;
    hipLaunchKernelGGL(pack_cols, dim3((n + 255) / 256), dim3(256), 0, stream,
                       src, dst, rows, cols, sld, dld, off);
  };
  packs(sWg_f, packS, 128, 256, 256, 768, 0);
  packs(sWc_f, packS, 128, 128, 128, 768, 256);
  packs(sWg_b, packS, 128, 256, 256, 768, 384);
  packs(sWc_b, packS, 128, 128, 128, 768, 640);
  packs(dWg_f, packD, 256, 512, 512, 1536, 0);
  packs(dWc_f, packD, 256, 256, 256, 1536, 512);
  packs(dWg_b, packD, 256, 512, 512, 1536, 768);
  packs(dWc_b, packD, 256, 256, 256, 1536, 1280);

  // embProj = emb @ packS  [50000,768]
  hipLaunchKernelGGL(gemm_f32, dim3(12, 782), dim3(256), 0, stream,
                     emb, packS, embProj, 50000, 768, 128);

  // sentence bi-GRU -> sent [2048,256]
  hipLaunchKernelGGL(sent_gru, dim3(128, 2), dim3(256), 0, stream,
                     X, L, embProj,
                     sWg_f, sbg_f, sWc_f, sbc_f,
                     sWg_b, sbg_b, sWc_b, sbc_b, sent);

  // xprojD = sent @ packD  [2048,1536], K=256
  hipLaunchKernelGGL(gemm_f32, dim3(24, 32), dim3(256), 0, stream,
                     sent, packD, xprojD, 2048, 1536, 256);

  hipLaunchKernelGGL(doc_gru, dim3(16, 2), dim3(512), 0, stream,
                     xprojD, L2,
                     dWg_f, dbg_f, dWc_f, dbc_f,
                     dWg_b, dbg_b, dWc_b, dbc_b, docv);

  hipLaunchKernelGGL(mlp_head, dim3(64), dim3(256), 0, stream,
                     docv, W1, b1, W2, b2, out);
}

// Round 5
// 986.324 us; speedup vs baseline: 1.8802x; 1.1188x over previous
//
#include <hip/hip_runtime.h>
#include <cstdint>
#include <cstddef>

// ---------------------------------------------------------------------------
// TreeModel: hierarchical bi-GRU (sentence + doc) + MLP head. Round 5:
//   - FIX round-4 crash: doc h-part weight base is +256 rows (not +512) —
//     round 4 read 512KB past the end of dWg/dWc -> device fault.
//   - doc_gru_mfma moved to f16 MFMA (weights f16-hi in VGPRs, A split
//     hi/lo 2-pass): 8x less weight-quantization error than bf16-hi.
//   - emb_gemm (MFMA split-bf16 3-pass), sent_gru (round-3, exact),
//     gemm_f32, mlp_head unchanged.
// ---------------------------------------------------------------------------

typedef __attribute__((ext_vector_type(8))) short bf16x8;     // 8 bf16 = 4 VGPR
typedef __attribute__((ext_vector_type(8))) _Float16 f16x8;   // 8 f16  = 4 VGPR
typedef __attribute__((ext_vector_type(4))) float f32x4;      // C/D frag

__device__ __forceinline__ void split_bf16(float f, short& hi, short& lo) {
  unsigned u = __float_as_uint(f);
  unsigned rb = (u + 0x7FFFu + ((u >> 16) & 1u)) & 0xFFFF0000u;  // RNE
  hi = (short)(rb >> 16);
  float r = f - __uint_as_float(rb);
  unsigned ur = __float_as_uint(r);
  lo = (short)((ur + 0x7FFFu + ((ur >> 16) & 1u)) >> 16);
}

__device__ __forceinline__ void split_f16(float f, short& hi, short& lo) {
  _Float16 h = (_Float16)f;                    // RNE
  hi = __builtin_bit_cast(short, h);
  _Float16 l = (_Float16)(f - (float)h);
  lo = __builtin_bit_cast(short, l);
}

__device__ __forceinline__ float sigm(float x) { return 1.f / (1.f + __expf(-x)); }
__device__ __forceinline__ float tanh_fast(float x) {
  float e = __expf(2.f * x);
  return 1.f - 2.f / (e + 1.f);
}

__global__ void pack_cols(const float* __restrict__ src, float* __restrict__ dst,
                          int rows, int cols, int src_ld, int dst_ld, int coloff) {
  int i = blockIdx.x * 256 + threadIdx.x;
  if (i < rows * cols) {
    int r = i / cols, c = i - r * cols;
    dst[(size_t)r * dst_ld + coloff + c] = src[(size_t)r * src_ld + c];
  }
}

// Build transposed, split-bf16 B for embProj: Bt[n][k], n in [0,768), k in [0,128)
__global__ void bt_prep(const float* __restrict__ sWg_f, const float* __restrict__ sWc_f,
                        const float* __restrict__ sWg_b, const float* __restrict__ sWc_b,
                        short* __restrict__ BtHi, short* __restrict__ BtLo) {
  int i = blockIdx.x * 256 + threadIdx.x;
  if (i >= 768 * 128) return;
  int n = i >> 7, k = i & 127;
  float f;
  if (n < 256) f = sWg_f[k * 256 + n];
  else if (n < 384) f = sWc_f[k * 128 + (n - 256)];
  else if (n < 640) f = sWg_b[k * 256 + (n - 384)];
  else f = sWc_b[k * 128 + (n - 640)];
  short hi, lo;
  split_bf16(f, hi, lo);
  BtHi[i] = hi;
  BtLo[i] = lo;
}

// ---------------------------------------------------------------------------
// embProj[50000,768] = emb[50000,128] @ packS[128,768], MFMA 3-pass split-bf16.
// ---------------------------------------------------------------------------
__global__ __launch_bounds__(256, 1) void emb_gemm(
    const float* __restrict__ emb, const short* __restrict__ BtHi,
    const short* __restrict__ BtLo, float* __restrict__ C) {
  const int tid = threadIdx.x;
  const int w = tid >> 6, l = tid & 63, li = l & 15, g = l >> 4;
  const int m0 = blockIdx.x * 64;

  bf16x8 ahi[4][4], alo[4][4];
#pragma unroll
  for (int mt = 0; mt < 4; ++mt) {
    int row = m0 + 16 * mt + li;
    if (row > 49999) row = 49999;
    const float* ap = emb + (size_t)row * 128 + 8 * g;
#pragma unroll
    for (int kk = 0; kk < 4; ++kk) {
      float4 v0 = *(const float4*)(ap + 32 * kk);
      float4 v1 = *(const float4*)(ap + 32 * kk + 4);
      float vv[8] = {v0.x, v0.y, v0.z, v0.w, v1.x, v1.y, v1.z, v1.w};
#pragma unroll
      for (int e = 0; e < 8; ++e) {
        short hi, lo;
        split_bf16(vv[e], hi, lo);
        ahi[mt][kk][e] = hi;
        alo[mt][kk][e] = lo;
      }
    }
  }

  f32x4 acc[4][12];
#pragma unroll
  for (int mt = 0; mt < 4; ++mt)
#pragma unroll
    for (int nt = 0; nt < 12; ++nt) acc[mt][nt] = (f32x4){0.f, 0.f, 0.f, 0.f};

#pragma unroll
  for (int nt = 0; nt < 12; ++nt) {
    const int col = 192 * w + 16 * nt + li;
    const short* bh = BtHi + col * 128 + 8 * g;
    const short* bl = BtLo + col * 128 + 8 * g;
    bf16x8 bhi[4], blo[4];
#pragma unroll
    for (int kk = 0; kk < 4; ++kk) {
      bhi[kk] = *(const bf16x8*)(bh + 32 * kk);
      blo[kk] = *(const bf16x8*)(bl + 32 * kk);
    }
#pragma unroll
    for (int kk = 0; kk < 4; ++kk)
#pragma unroll
      for (int mt = 0; mt < 4; ++mt) {
        acc[mt][nt] = __builtin_amdgcn_mfma_f32_16x16x32_bf16(alo[mt][kk], bhi[kk], acc[mt][nt], 0, 0, 0);
        acc[mt][nt] = __builtin_amdgcn_mfma_f32_16x16x32_bf16(ahi[mt][kk], blo[kk], acc[mt][nt], 0, 0, 0);
        acc[mt][nt] = __builtin_amdgcn_mfma_f32_16x16x32_bf16(ahi[mt][kk], bhi[kk], acc[mt][nt], 0, 0, 0);
      }
  }

#pragma unroll
  for (int mt = 0; mt < 4; ++mt)
#pragma unroll
    for (int nt = 0; nt < 12; ++nt) {
      const int col = 192 * w + 16 * nt + li;
#pragma unroll
      for (int r = 0; r < 4; ++r) {
        int row = m0 + 16 * mt + 4 * g + r;
        if (row < 50000) C[(size_t)row * 768 + col] = acc[mt][nt][r];
      }
    }
}

// C[M,N] = A[M,K] @ B[K,N]; N%64==0, K%128==0; M guarded. (used for xprojD)
__global__ __launch_bounds__(256) void gemm_f32(
    const float* __restrict__ A, const float* __restrict__ B, float* __restrict__ C,
    int M, int N, int K) {
  __shared__ float As[64][132];
  __shared__ float Bs[128][64];
  const int tid = threadIdx.x;
  const int bn = blockIdx.x * 64, bm = blockIdx.y * 64;
  const int tx = tid & 15, ty = tid >> 4;
  const int tm = ty * 4, tn = tx * 4;
  float acc[4][4] = {};
  for (int k0 = 0; k0 < K; k0 += 128) {
#pragma unroll
    for (int i = 0; i < 8; ++i) {
      int q = tid + 256 * i;
      int r = q >> 5, c4 = (q & 31) << 2;
      float4 v;
      if (bm + r < M) v = *(const float4*)(A + (size_t)(bm + r) * K + k0 + c4);
      else v = make_float4(0.f, 0.f, 0.f, 0.f);
      *(float4*)&As[r][c4] = v;
    }
#pragma unroll
    for (int i = 0; i < 8; ++i) {
      int q = tid + 256 * i;
      int r = q >> 4, c4 = (q & 15) << 2;
      *(float4*)&Bs[r][c4] = *(const float4*)(B + (size_t)(k0 + r) * N + bn + c4);
    }
    __syncthreads();
#pragma unroll
    for (int kq = 0; kq < 32; ++kq) {
      float4 av[4], bv[4];
#pragma unroll
      for (int i = 0; i < 4; ++i) av[i] = *(const float4*)&As[tm + i][kq * 4];
#pragma unroll
      for (int kk = 0; kk < 4; ++kk) bv[kk] = *(const float4*)&Bs[kq * 4 + kk][tn];
#pragma unroll
      for (int i = 0; i < 4; ++i) {
        const float* ap = (const float*)&av[i];
#pragma unroll
        for (int kk = 0; kk < 4; ++kk) {
          float a = ap[kk];
          const float* bp = (const float*)&bv[kk];
#pragma unroll
          for (int jj = 0; jj < 4; ++jj) acc[i][jj] += a * bp[jj];
        }
      }
    }
    __syncthreads();
  }
#pragma unroll
  for (int i = 0; i < 4; ++i) {
    int row = bm + tm + i;
    if (row < M)
      *(float4*)(C + (size_t)row * N + bn + tn) =
          make_float4(acc[i][0], acc[i][1], acc[i][2], acc[i][3]);
  }
}

// ---------------------------------------------------------------------------
// Sentence GRU, MFMA (round 3, unchanged). grid (128,2), block 256.
// ---------------------------------------------------------------------------
#define SENTS 16

__global__ __launch_bounds__(256, 1) void sent_gru(
    const int* __restrict__ X, const int* __restrict__ L,
    const float* __restrict__ embProj,
    const float* __restrict__ Wg_f, const float* __restrict__ bg_f,
    const float* __restrict__ Wc_f, const float* __restrict__ bc_f,
    const float* __restrict__ Wg_b, const float* __restrict__ bg_b,
    const float* __restrict__ Wc_b, const float* __restrict__ bc_b,
    float* __restrict__ sent) {
  const int dir = blockIdx.y;
  const int g0 = blockIdx.x * SENTS;
  const int tid = threadIdx.x;
  const int w = tid >> 6, l = tid & 63;
  const int li = l & 15, g = l >> 4;
  const float* Wg = dir ? Wg_b : Wg_f;
  const float* Wc = dir ? Wc_b : Wc_f;
  const float* bgp = dir ? bg_b : bg_f;
  const float* bcp = dir ? bc_b : bc_f;

  __shared__ float xbuf[2][SENTS][384];
  __shared__ float h_f[SENTS][132];
  __shared__ float u_f[SENTS][132];
  alignas(16) __shared__ short h_hi[SENTS][136], h_lo[SENTS][136];
  alignas(16) __shared__ short rh_hi[SENTS][136], rh_lo[SENTS][136];
  __shared__ int wid[2][SENTS];
  __shared__ int len_s[SENTS];

  bf16x8 bgh[4][4], bgl[4][4];
  bf16x8 bch[2][4], bcl[2][4];
#pragma unroll
  for (int nt = 0; nt < 4; ++nt)
#pragma unroll
    for (int kk = 0; kk < 4; ++kk) {
      const float* base = Wg + (size_t)(128 + 32 * kk + 8 * g) * 256 + 64 * w + 16 * nt + li;
#pragma unroll
      for (int e = 0; e < 8; ++e) {
        short hi, lo;
        split_bf16(base[(size_t)e * 256], hi, lo);
        bgh[nt][kk][e] = hi; bgl[nt][kk][e] = lo;
      }
    }
#pragma unroll
  for (int ct = 0; ct < 2; ++ct)
#pragma unroll
    for (int kk = 0; kk < 4; ++kk) {
      const float* base = Wc + (size_t)(128 + 32 * kk + 8 * g) * 128 + 32 * w + 16 * ct + li;
#pragma unroll
      for (int e = 0; e < 8; ++e) {
        short hi, lo;
        split_bf16(base[(size_t)e * 128], hi, lo);
        bch[ct][kk][e] = hi; bcl[ct][kk][e] = lo;
      }
    }
  float bgj[4], bcj[2];
#pragma unroll
  for (int nt = 0; nt < 4; ++nt) bgj[nt] = bgp[64 * w + 16 * nt + li];
#pragma unroll
  for (int ct = 0; ct < 2; ++ct) bcj[ct] = bcp[32 * w + 16 * ct + li];

  if (tid < SENTS) {
    int ll = L[g0 + tid];
    len_s[tid] = ll;
    wid[0][tid] = X[(g0 + tid) * 64 + (dir ? (ll - 1) : 0)];
    wid[1][tid] = (1 < ll) ? X[(g0 + tid) * 64 + (dir ? (ll - 2) : 1)] : 0;
  }
  for (int q = tid; q < SENTS * 136; q += 256) {
    ((short*)h_hi)[q] = 0; ((short*)h_lo)[q] = 0;
  }
  for (int q = tid; q < SENTS * 132; q += 256) ((float*)h_f)[q] = 0.f;
  __syncthreads();

  int lens4[4];
#pragma unroll
  for (int r = 0; r < 4; ++r) lens4[r] = len_s[4 * g + r];
  int maxlen = 0;
#pragma unroll
  for (int m = 0; m < SENTS; ++m) maxlen = max(maxlen, len_s[m]);

  auto prefetch_x = [&](int t) {
    int b = t & 1;
#pragma unroll
    for (int c = 0; c < 6; ++c) {
      int q = tid + 256 * c;
      int m = q / 96, s = q - m * 96;
      const float* src = embProj + (size_t)wid[b][m] * 768 + dir * 384 + s * 4;
      float* dst = (float*)&xbuf[b][0][0] + q * 4;
      __builtin_amdgcn_global_load_lds(
          (const __attribute__((address_space(1))) void*)src,
          (__attribute__((address_space(3))) void*)dst, 16, 0, 0);
    }
  };

  prefetch_x(0);
  __syncthreads();

  for (int t = 0; t < maxlen; ++t) {
    const int cur = t & 1;
    prefetch_x(t + 1);
    if (tid < SENTS) {
      int ll = len_s[tid], tt = t + 2;
      wid[tt & 1][tid] = (tt < ll) ? X[(g0 + tid) * 64 + (dir ? (ll - 1 - tt) : tt)] : 0;
    }

    bf16x8 a_hi[4], a_lo[4];
#pragma unroll
    for (int kk = 0; kk < 4; ++kk) {
      a_hi[kk] = *(const bf16x8*)&h_hi[li][32 * kk + 8 * g];
      a_lo[kk] = *(const bf16x8*)&h_lo[li][32 * kk + 8 * g];
    }
    f32x4 accg[4];
#pragma unroll
    for (int nt = 0; nt < 4; ++nt) {
      const int col = 64 * w + 16 * nt + li;
      f32x4 c;
#pragma unroll
      for (int r = 0; r < 4; ++r) c[r] = bgj[nt] + xbuf[cur][4 * g + r][col];
#pragma unroll
      for (int kk = 0; kk < 4; ++kk) {
        c = __builtin_amdgcn_mfma_f32_16x16x32_bf16(a_hi[kk], bgh[nt][kk], c, 0, 0, 0);
        c = __builtin_amdgcn_mfma_f32_16x16x32_bf16(a_hi[kk], bgl[nt][kk], c, 0, 0, 0);
        c = __builtin_amdgcn_mfma_f32_16x16x32_bf16(a_lo[kk], bgh[nt][kk], c, 0, 0, 0);
      }
      accg[nt] = c;
    }
    if (w < 2) {
#pragma unroll
      for (int nt = 0; nt < 4; ++nt) {
        const int col = 64 * w + 16 * nt + li;
#pragma unroll
        for (int r = 0; r < 4; ++r) {
          const int row = 4 * g + r;
          float s = sigm(accg[nt][r]);
          float rh = s * h_f[row][col];
          short hi, lo;
          split_bf16(rh, hi, lo);
          rh_hi[row][col] = hi;
          rh_lo[row][col] = lo;
        }
      }
    } else {
#pragma unroll
      for (int nt = 0; nt < 4; ++nt) {
        const int col = 64 * (w - 2) + 16 * nt + li;
#pragma unroll
        for (int r = 0; r < 4; ++r) {
          u_f[4 * g + r][col] = sigm(accg[nt][r]);
        }
      }
    }
    __syncthreads();

    bf16x8 ra_hi[4], ra_lo[4];
#pragma unroll
    for (int kk = 0; kk < 4; ++kk) {
      ra_hi[kk] = *(const bf16x8*)&rh_hi[li][32 * kk + 8 * g];
      ra_lo[kk] = *(const bf16x8*)&rh_lo[li][32 * kk + 8 * g];
    }
#pragma unroll
    for (int ct = 0; ct < 2; ++ct) {
      const int col = 32 * w + 16 * ct + li;
      f32x4 c;
#pragma unroll
      for (int r = 0; r < 4; ++r) c[r] = bcj[ct] + xbuf[cur][4 * g + r][256 + col];
#pragma unroll
      for (int kk = 0; kk < 4; ++kk) {
        c = __builtin_amdgcn_mfma_f32_16x16x32_bf16(ra_hi[kk], bch[ct][kk], c, 0, 0, 0);
        c = __builtin_amdgcn_mfma_f32_16x16x32_bf16(ra_hi[kk], bcl[ct][kk], c, 0, 0, 0);
        c = __builtin_amdgcn_mfma_f32_16x16x32_bf16(ra_lo[kk], bch[ct][kk], c, 0, 0, 0);
      }
#pragma unroll
      for (int r = 0; r < 4; ++r) {
        const int row = 4 * g + r;
        float cand = tanh_fast(c[r]);
        float u = u_f[row][col];
        float hold = h_f[row][col];
        float hn = u * hold + (1.f - u) * cand;
        hn = (t < lens4[r]) ? hn : hold;
        h_f[row][col] = hn;
        short hi, lo;
        split_bf16(hn, hi, lo);
        h_hi[row][col] = hi;
        h_lo[row][col] = lo;
      }
    }
    __syncthreads();
  }

  for (int q = tid; q < SENTS * 128; q += 256) {
    int m = q >> 7, j = q & 127;
    sent[(size_t)(g0 + m) * 256 + dir * 128 + j] = h_f[m][j];
  }
}

// ---------------------------------------------------------------------------
// Doc GRU, f16 MFMA. grid (4, 2), block 256 = 4 waves (1 wave/SIMD).
// 16 docs/block. H=256. Weights: f16 (RNE) hi-plane in VGPRs; A (h, rh)
// split f16 hi/lo, 2-pass MFMA. dWg=[512,512] (x rows 0..255, h rows
// 256..511), dWc=[512,256].
// ---------------------------------------------------------------------------
#define DOCS 16

__global__ __launch_bounds__(256, 1) void doc_gru_mfma(
    const float* __restrict__ xprojD, const int* __restrict__ L2,
    const float* __restrict__ dWg_f, const float* __restrict__ dbg_f,
    const float* __restrict__ dWc_f, const float* __restrict__ dbc_f,
    const float* __restrict__ dWg_b, const float* __restrict__ dbg_b,
    const float* __restrict__ dWc_b, const float* __restrict__ dbc_b,
    float* __restrict__ docv) {
  const int dir = blockIdx.y;
  const int g0 = blockIdx.x * DOCS;
  const int tid = threadIdx.x;
  const int w = tid >> 6, l = tid & 63, li = l & 15, g = l >> 4;
  const float* Wg = dir ? dWg_b : dWg_f;   // [512,512]
  const float* Wc = dir ? dWc_b : dWc_f;   // [512,256]
  const float* bgp = dir ? dbg_b : dbg_f;
  const float* bcp = dir ? dbc_b : dbc_f;
  const int xoff = dir ? 768 : 0;

  alignas(16) __shared__ short h_hi[DOCS][264], h_lo[DOCS][264];
  alignas(16) __shared__ short rh_hi[DOCS][264], rh_lo[DOCS][264];
  __shared__ float h_f[DOCS][256], u_f[DOCS][256];
  __shared__ int len_s[DOCS];

  // ---- one-time: h-part weights (f16 hi plane) into VGPRs ----
  f16x8 wg[8][8];   // gates: [nt][kk], col = 128w+16nt+li, k = 32kk+8g+e
  f16x8 wc[4][8];   // cand:  [nt][kk], col = 64w+16nt+li
  const float* Wg_h = Wg + 256 * 512;   // h-part rows (FIX: was +512*512)
  const float* Wc_h = Wc + 256 * 256;   // h-part rows (FIX: was +512*256)
#pragma unroll
  for (int nt = 0; nt < 8; ++nt)
#pragma unroll
    for (int kk = 0; kk < 8; ++kk) {
      const float* base = Wg_h + (size_t)(32 * kk + 8 * g) * 512 + 128 * w + 16 * nt + li;
#pragma unroll
      for (int e = 0; e < 8; ++e) wg[nt][kk][e] = (_Float16)base[(size_t)e * 512];
    }
#pragma unroll
  for (int nt = 0; nt < 4; ++nt)
#pragma unroll
    for (int kk = 0; kk < 8; ++kk) {
      const float* base = Wc_h + (size_t)(32 * kk + 8 * g) * 256 + 64 * w + 16 * nt + li;
#pragma unroll
      for (int e = 0; e < 8; ++e) wc[nt][kk][e] = (_Float16)base[(size_t)e * 256];
    }
  float bgj[8], bcj[4];
#pragma unroll
  for (int nt = 0; nt < 8; ++nt) bgj[nt] = bgp[128 * w + 16 * nt + li];
#pragma unroll
  for (int nt = 0; nt < 4; ++nt) bcj[nt] = bcp[64 * w + 16 * nt + li];

  if (tid < DOCS) len_s[tid] = L2[g0 + tid];
  for (int q = tid; q < DOCS * 264; q += 256) {
    ((short*)h_hi)[q] = 0; ((short*)h_lo)[q] = 0;
  }
  for (int q = tid; q < DOCS * 256; q += 256) {
    ((float*)h_f)[q] = 0.f; ((float*)u_f)[q] = 0.f;
  }
  __syncthreads();

  int lens4[4];
#pragma unroll
  for (int r = 0; r < 4; ++r) lens4[r] = len_s[4 * g + r];
  int maxlen = 0;
#pragma unroll
  for (int m = 0; m < DOCS; ++m) maxlen = max(maxlen, len_s[m]);

  for (int t = 0; t < maxlen; ++t) {
    size_t xbase[4];
#pragma unroll
    for (int r = 0; r < 4; ++r) {
      int ti = dir ? max(lens4[r] - 1 - t, 0) : t;
      xbase[r] = ((size_t)(g0 + 4 * g + r) * 32 + ti) * 1536 + xoff;
    }

    // ---- gates ----
    f32x4 acc[8];
#pragma unroll
    for (int nt = 0; nt < 8; ++nt) {
      const int col = 128 * w + 16 * nt + li;
#pragma unroll
      for (int r = 0; r < 4; ++r) acc[nt][r] = bgj[nt] + xprojD[xbase[r] + col];
    }
#pragma unroll
    for (int half = 0; half < 2; ++half) {
      f16x8 ah[4], al[4];
#pragma unroll
      for (int c = 0; c < 4; ++c) {
        ah[c] = *(const f16x8*)&h_hi[li][32 * (4 * half + c) + 8 * g];
        al[c] = *(const f16x8*)&h_lo[li][32 * (4 * half + c) + 8 * g];
      }
#pragma unroll
      for (int c = 0; c < 4; ++c)
#pragma unroll
        for (int nt = 0; nt < 8; ++nt) {
          acc[nt] = __builtin_amdgcn_mfma_f32_16x16x32_f16(al[c], wg[nt][4 * half + c], acc[nt], 0, 0, 0);
          acc[nt] = __builtin_amdgcn_mfma_f32_16x16x32_f16(ah[c], wg[nt][4 * half + c], acc[nt], 0, 0, 0);
        }
    }
    if (w < 2) {               // r-gate columns -> rh (split f16 hi/lo)
#pragma unroll
      for (int nt = 0; nt < 8; ++nt) {
        const int col = 128 * w + 16 * nt + li;
#pragma unroll
        for (int r = 0; r < 4; ++r) {
          const int m = 4 * g + r;
          float s = sigm(acc[nt][r]);
          float rh = s * h_f[m][col];
          short hi, lo;
          split_f16(rh, hi, lo);
          rh_hi[m][col] = hi;
          rh_lo[m][col] = lo;
        }
      }
    } else {                   // u-gate columns
#pragma unroll
      for (int nt = 0; nt < 8; ++nt) {
        const int col = 128 * (w - 2) + 16 * nt + li;
#pragma unroll
        for (int r = 0; r < 4; ++r) u_f[4 * g + r][col] = sigm(acc[nt][r]);
      }
    }
    __syncthreads();

    // ---- candidate ----
    f32x4 acc2[4];
#pragma unroll
    for (int nt = 0; nt < 4; ++nt) {
      const int col = 64 * w + 16 * nt + li;
#pragma unroll
      for (int r = 0; r < 4; ++r) acc2[nt][r] = bcj[nt] + xprojD[xbase[r] + 512 + col];
    }
#pragma unroll
    for (int half = 0; half < 2; ++half) {
      f16x8 ah[4], al[4];
#pragma unroll
      for (int c = 0; c < 4; ++c) {
        ah[c] = *(const f16x8*)&rh_hi[li][32 * (4 * half + c) + 8 * g];
        al[c] = *(const f16x8*)&rh_lo[li][32 * (4 * half + c) + 8 * g];
      }
#pragma unroll
      for (int c = 0; c < 4; ++c)
#pragma unroll
        for (int nt = 0; nt < 4; ++nt) {
          acc2[nt] = __builtin_amdgcn_mfma_f32_16x16x32_f16(al[c], wc[nt][4 * half + c], acc2[nt], 0, 0, 0);
          acc2[nt] = __builtin_amdgcn_mfma_f32_16x16x32_f16(ah[c], wc[nt][4 * half + c], acc2[nt], 0, 0, 0);
        }
    }
#pragma unroll
    for (int nt = 0; nt < 4; ++nt) {
      const int col = 64 * w + 16 * nt + li;
#pragma unroll
      for (int r = 0; r < 4; ++r) {
        const int m = 4 * g + r;
        float cand = tanh_fast(acc2[nt][r]);
        float u = u_f[m][col];
        float hold = h_f[m][col];
        float hn = u * hold + (1.f - u) * cand;
        hn = (t < lens4[r]) ? hn : hold;
        h_f[m][col] = hn;
        short hi, lo;
        split_f16(hn, hi, lo);
        h_hi[m][col] = hi;
        h_lo[m][col] = lo;
      }
    }
    __syncthreads();
  }

  for (int q = tid; q < DOCS * 256; q += 256) {
    int m = q >> 8, j = q & 255;
    docv[(size_t)(g0 + m) * 512 + dir * 256 + j] = h_f[m][j];
  }
}

__global__ __launch_bounds__(256) void mlp_head(
    const float* __restrict__ docv, const float* __restrict__ W1,
    const float* __restrict__ b1, const float* __restrict__ W2,
    const float* __restrict__ b2, float* __restrict__ out) {
  const int b = blockIdx.x, j = threadIdx.x;
  __shared__ float hid[256];
  float acc = b1[j];
#pragma unroll 4
  for (int k = 0; k < 512; ++k) acc += docv[b * 512 + k] * W1[k * 256 + j];
  hid[j] = fmaxf(acc, 0.f);
  __syncthreads();
  if (j < 5) {
    float a = b2[j];
#pragma unroll 4
    for (int k = 0; k < 256; ++k) a += hid[k] * W2[k * 5 + j];
    out[b * 5 + j] = a;
  }
}

extern "C" void kernel_launch(void* const* d_in, const int* in_sizes, int n_in,
                              void* d_out, int out_size, void* d_ws, size_t ws_size,
                              hipStream_t stream) {
  const int* X = (const int*)d_in[0];
  const int* L = (const int*)d_in[1];
  const int* L2 = (const int*)d_in[2];
  const float* emb = (const float*)d_in[3];
  const float* sWg_f = (const float*)d_in[4];
  const float* sbg_f = (const float*)d_in[5];
  const float* sWc_f = (const float*)d_in[6];
  const float* sbc_f = (const float*)d_in[7];
  const float* sWg_b = (const float*)d_in[8];
  const float* sbg_b = (const float*)d_in[9];
  const float* sWc_b = (const float*)d_in[10];
  const float* sbc_b = (const float*)d_in[11];
  const float* dWg_f = (const float*)d_in[12];
  const float* dbg_f = (const float*)d_in[13];
  const float* dWc_f = (const float*)d_in[14];
  const float* dbc_f = (const float*)d_in[15];
  const float* dWg_b = (const float*)d_in[16];
  const float* dbg_b = (const float*)d_in[17];
  const float* dWc_b = (const float*)d_in[18];
  const float* dbc_b = (const float*)d_in[19];
  const float* W1 = (const float*)d_in[20];
  const float* b1 = (const float*)d_in[21];
  const float* W2 = (const float*)d_in[22];
  const float* b2 = (const float*)d_in[23];
  float* out = (float*)d_out;

  float* ws = (float*)d_ws;
  float* embProj = ws;                       // 50000*768
  float* sent = embProj + 38400000;          // 2048*256
  float* xprojD = sent + 524288;             // 2048*1536
  float* docv = xprojD + 3145728;            // 64*512
  float* packD = docv + 32768;               // 256*1536
  short* BtHi = (short*)(packD + 393216);    // 768*128 bf16
  short* BtLo = BtHi + 98304;                // 768*128 bf16

  // B-transpose-split for embProj GEMM
  hipLaunchKernelGGL(bt_prep, dim3(384), dim3(256), 0, stream,
                     sWg_f, sWc_f, sWg_b, sWc_b, BtHi, BtLo);

  // pack doc-level x-part weight columns -> packD [256,1536]
  auto packs = [&](const float* src, float* dst, int rows, int cols, int sld,
                   int dld, int off) {
    int n = rows * cols;
    hipLaunchKernelGGL(pack_cols, dim3((n + 255) / 256), dim3(256), 0, stream,
                       src, dst, rows, cols, sld, dld, off);
  };
  packs(dWg_f, packD, 256, 512, 512, 1536, 0);
  packs(dWc_f, packD, 256, 256, 256, 1536, 512);
  packs(dWg_b, packD, 256, 512, 512, 1536, 768);
  packs(dWc_b, packD, 256, 256, 256, 1536, 1280);

  // embProj = emb @ packS  [50000,768] (MFMA split-bf16)
  hipLaunchKernelGGL(emb_gemm, dim3(782), dim3(256), 0, stream,
                     emb, BtHi, BtLo, embProj);

  // sentence bi-GRU -> sent [2048,256]
  hipLaunchKernelGGL(sent_gru, dim3(128, 2), dim3(256), 0, stream,
                     X, L, embProj,
                     sWg_f, sbg_f, sWc_f, sbc_f,
                     sWg_b, sbg_b, sWc_b, sbc_b, sent);

  // xprojD = sent @ packD  [2048,1536], K=256
  hipLaunchKernelGGL(gemm_f32, dim3(24, 32), dim3(256), 0, stream,
                     sent, packD, xprojD, 2048, 1536, 256);

  // doc bi-GRU -> docv [64,512]
  hipLaunchKernelGGL(doc_gru_mfma, dim3(4, 2), dim3(256), 0, stream,
                     xprojD, L2,
                     dWg_f, dbg_f, dWc_f, dbc_f,
                     dWg_b, dbg_b, dWc_b, dbc_b, docv);

  hipLaunchKernelGGL(mlp_head, dim3(64), dim3(256), 0, stream,
                     docv, W1, b1, W2, b2, out);
}

// Round 6
// 773.429 us; speedup vs baseline: 2.3978x; 1.2753x over previous
//
#include <hip/hip_runtime.h>
#include <cstdint>
#include <cstddef>

// ---------------------------------------------------------------------------
// TreeModel: hierarchical bi-GRU (sentence + doc) + MLP head. Round 6:
//   - doc_gru_mfma v3: 8 waves/block, 192 VGPR of weights per thread
//     (fits: round-5's 384 VGPR demand spilled -> 15us/step remat).
//   - xprojD GEMM -> MFMA split-bf16 3-pass (xproj_gemm); sent_gru now
//     emits bf16 hi/lo planes directly (f32 sent buffer dropped).
//   - emb_gemm, sent_gru core, mlp_head unchanged.
// ---------------------------------------------------------------------------

typedef __attribute__((ext_vector_type(8))) short bf16x8;     // 8 bf16 = 4 VGPR
typedef __attribute__((ext_vector_type(8))) _Float16 f16x8;   // 8 f16  = 4 VGPR
typedef __attribute__((ext_vector_type(4))) float f32x4;      // C/D frag

__device__ __forceinline__ void split_bf16(float f, short& hi, short& lo) {
  unsigned u = __float_as_uint(f);
  unsigned rb = (u + 0x7FFFu + ((u >> 16) & 1u)) & 0xFFFF0000u;  // RNE
  hi = (short)(rb >> 16);
  float r = f - __uint_as_float(rb);
  unsigned ur = __float_as_uint(r);
  lo = (short)((ur + 0x7FFFu + ((ur >> 16) & 1u)) >> 16);
}

__device__ __forceinline__ void split_f16(float f, short& hi, short& lo) {
  _Float16 h = (_Float16)f;                    // RNE
  hi = __builtin_bit_cast(short, h);
  _Float16 l = (_Float16)(f - (float)h);
  lo = __builtin_bit_cast(short, l);
}

__device__ __forceinline__ float sigm(float x) { return 1.f / (1.f + __expf(-x)); }
__device__ __forceinline__ float tanh_fast(float x) {
  float e = __expf(2.f * x);
  return 1.f - 2.f / (e + 1.f);
}

// Build transposed, split-bf16 B for embProj: Bt[n][k], n in [0,768), k in [0,128)
__global__ void bt_prep(const float* __restrict__ sWg_f, const float* __restrict__ sWc_f,
                        const float* __restrict__ sWg_b, const float* __restrict__ sWc_b,
                        short* __restrict__ BtHi, short* __restrict__ BtLo) {
  int i = blockIdx.x * 256 + threadIdx.x;
  if (i >= 768 * 128) return;
  int n = i >> 7, k = i & 127;
  float f;
  if (n < 256) f = sWg_f[k * 256 + n];
  else if (n < 384) f = sWc_f[k * 128 + (n - 256)];
  else if (n < 640) f = sWg_b[k * 256 + (n - 384)];
  else f = sWc_b[k * 128 + (n - 640)];
  short hi, lo;
  split_bf16(f, hi, lo);
  BtHi[i] = hi;
  BtLo[i] = lo;
}

// Transposed split-bf16 planes of doc x-part weights: PdT[n][k], n in [0,1536),
// k in [0,256). n layout: [dWg_f 512 | dWc_f 256 | dWg_b 512 | dWc_b 256].
__global__ void packdt_prep(const float* __restrict__ dWg_f, const float* __restrict__ dWc_f,
                            const float* __restrict__ dWg_b, const float* __restrict__ dWc_b,
                            short* __restrict__ Hi, short* __restrict__ Lo) {
  int i = blockIdx.x * 256 + threadIdx.x;
  if (i >= 1536 * 256) return;
  int n = i >> 8, k = i & 255;
  float f;
  if (n < 512) f = dWg_f[k * 512 + n];
  else if (n < 768) f = dWc_f[k * 256 + (n - 512)];
  else if (n < 1280) f = dWg_b[k * 512 + (n - 768)];
  else f = dWc_b[k * 256 + (n - 1280)];
  short hi, lo;
  split_bf16(f, hi, lo);
  Hi[i] = hi;
  Lo[i] = lo;
}

// ---------------------------------------------------------------------------
// embProj[50000,768] = emb[50000,128] @ packS[128,768], MFMA 3-pass split-bf16.
// ---------------------------------------------------------------------------
__global__ __launch_bounds__(256, 1) void emb_gemm(
    const float* __restrict__ emb, const short* __restrict__ BtHi,
    const short* __restrict__ BtLo, float* __restrict__ C) {
  const int tid = threadIdx.x;
  const int w = tid >> 6, l = tid & 63, li = l & 15, g = l >> 4;
  const int m0 = blockIdx.x * 64;

  bf16x8 ahi[4][4], alo[4][4];
#pragma unroll
  for (int mt = 0; mt < 4; ++mt) {
    int row = m0 + 16 * mt + li;
    if (row > 49999) row = 49999;
    const float* ap = emb + (size_t)row * 128 + 8 * g;
#pragma unroll
    for (int kk = 0; kk < 4; ++kk) {
      float4 v0 = *(const float4*)(ap + 32 * kk);
      float4 v1 = *(const float4*)(ap + 32 * kk + 4);
      float vv[8] = {v0.x, v0.y, v0.z, v0.w, v1.x, v1.y, v1.z, v1.w};
#pragma unroll
      for (int e = 0; e < 8; ++e) {
        short hi, lo;
        split_bf16(vv[e], hi, lo);
        ahi[mt][kk][e] = hi;
        alo[mt][kk][e] = lo;
      }
    }
  }

  f32x4 acc[4][12];
#pragma unroll
  for (int mt = 0; mt < 4; ++mt)
#pragma unroll
    for (int nt = 0; nt < 12; ++nt) acc[mt][nt] = (f32x4){0.f, 0.f, 0.f, 0.f};

#pragma unroll
  for (int nt = 0; nt < 12; ++nt) {
    const int col = 192 * w + 16 * nt + li;
    const short* bh = BtHi + col * 128 + 8 * g;
    const short* bl = BtLo + col * 128 + 8 * g;
    bf16x8 bhi[4], blo[4];
#pragma unroll
    for (int kk = 0; kk < 4; ++kk) {
      bhi[kk] = *(const bf16x8*)(bh + 32 * kk);
      blo[kk] = *(const bf16x8*)(bl + 32 * kk);
    }
#pragma unroll
    for (int kk = 0; kk < 4; ++kk)
#pragma unroll
      for (int mt = 0; mt < 4; ++mt) {
        acc[mt][nt] = __builtin_amdgcn_mfma_f32_16x16x32_bf16(alo[mt][kk], bhi[kk], acc[mt][nt], 0, 0, 0);
        acc[mt][nt] = __builtin_amdgcn_mfma_f32_16x16x32_bf16(ahi[mt][kk], blo[kk], acc[mt][nt], 0, 0, 0);
        acc[mt][nt] = __builtin_amdgcn_mfma_f32_16x16x32_bf16(ahi[mt][kk], bhi[kk], acc[mt][nt], 0, 0, 0);
      }
  }

#pragma unroll
  for (int mt = 0; mt < 4; ++mt)
#pragma unroll
    for (int nt = 0; nt < 12; ++nt) {
      const int col = 192 * w + 16 * nt + li;
#pragma unroll
      for (int r = 0; r < 4; ++r) {
        int row = m0 + 16 * mt + 4 * g + r;
        if (row < 50000) C[(size_t)row * 768 + col] = acc[mt][nt][r];
      }
    }
}

// ---------------------------------------------------------------------------
// xprojD[2048,1536] = sent[2048,256] @ packD[256,1536], MFMA 3-pass split-bf16.
// A from sentHi/sentLo planes, B from PdT planes. grid (32, 3), block 256.
// Wave w owns cols [by*512 + 128w, +128) (8 nt).
// ---------------------------------------------------------------------------
__global__ __launch_bounds__(256, 1) void xproj_gemm(
    const short* __restrict__ AHi, const short* __restrict__ ALo,
    const short* __restrict__ BtHi, const short* __restrict__ BtLo,
    float* __restrict__ C) {
  const int tid = threadIdx.x;
  const int w = tid >> 6, l = tid & 63, li = l & 15, g = l >> 4;
  const int m0 = blockIdx.x * 64;
  const int n0 = blockIdx.y * 512 + 128 * w;

  f32x4 acc[4][8];
#pragma unroll
  for (int mt = 0; mt < 4; ++mt)
#pragma unroll
    for (int nt = 0; nt < 8; ++nt) acc[mt][nt] = (f32x4){0.f, 0.f, 0.f, 0.f};

#pragma unroll
  for (int kk = 0; kk < 8; ++kk) {
    bf16x8 ah[4], al[4];
#pragma unroll
    for (int mt = 0; mt < 4; ++mt) {
      const int row = m0 + 16 * mt + li;
      ah[mt] = *(const bf16x8*)&AHi[(size_t)row * 256 + 32 * kk + 8 * g];
      al[mt] = *(const bf16x8*)&ALo[(size_t)row * 256 + 32 * kk + 8 * g];
    }
#pragma unroll
    for (int nt = 0; nt < 8; ++nt) {
      const int col = n0 + 16 * nt + li;
      bf16x8 bh = *(const bf16x8*)&BtHi[(size_t)col * 256 + 32 * kk + 8 * g];
      bf16x8 bl = *(const bf16x8*)&BtLo[(size_t)col * 256 + 32 * kk + 8 * g];
#pragma unroll
      for (int mt = 0; mt < 4; ++mt) {
        acc[mt][nt] = __builtin_amdgcn_mfma_f32_16x16x32_bf16(al[mt], bh, acc[mt][nt], 0, 0, 0);
        acc[mt][nt] = __builtin_amdgcn_mfma_f32_16x16x32_bf16(ah[mt], bl, acc[mt][nt], 0, 0, 0);
        acc[mt][nt] = __builtin_amdgcn_mfma_f32_16x16x32_bf16(ah[mt], bh, acc[mt][nt], 0, 0, 0);
      }
    }
  }

#pragma unroll
  for (int mt = 0; mt < 4; ++mt)
#pragma unroll
    for (int nt = 0; nt < 8; ++nt) {
      const int col = n0 + 16 * nt + li;
#pragma unroll
      for (int r = 0; r < 4; ++r) {
        int row = m0 + 16 * mt + 4 * g + r;
        C[(size_t)row * 1536 + col] = acc[mt][nt][r];
      }
    }
}

// ---------------------------------------------------------------------------
// Sentence GRU, MFMA (round 3 core). grid (128,2), block 256.
// Now emits bf16 hi/lo planes of the final h instead of f32 sent.
// ---------------------------------------------------------------------------
#define SENTS 16

__global__ __launch_bounds__(256, 1) void sent_gru(
    const int* __restrict__ X, const int* __restrict__ L,
    const float* __restrict__ embProj,
    const float* __restrict__ Wg_f, const float* __restrict__ bg_f,
    const float* __restrict__ Wc_f, const float* __restrict__ bc_f,
    const float* __restrict__ Wg_b, const float* __restrict__ bg_b,
    const float* __restrict__ Wc_b, const float* __restrict__ bc_b,
    short* __restrict__ sentHi, short* __restrict__ sentLo) {
  const int dir = blockIdx.y;
  const int g0 = blockIdx.x * SENTS;
  const int tid = threadIdx.x;
  const int w = tid >> 6, l = tid & 63;
  const int li = l & 15, g = l >> 4;
  const float* Wg = dir ? Wg_b : Wg_f;
  const float* Wc = dir ? Wc_b : Wc_f;
  const float* bgp = dir ? bg_b : bg_f;
  const float* bcp = dir ? bc_b : bc_f;

  __shared__ float xbuf[2][SENTS][384];
  __shared__ float h_f[SENTS][132];
  __shared__ float u_f[SENTS][132];
  alignas(16) __shared__ short h_hi[SENTS][136], h_lo[SENTS][136];
  alignas(16) __shared__ short rh_hi[SENTS][136], rh_lo[SENTS][136];
  __shared__ int wid[2][SENTS];
  __shared__ int len_s[SENTS];

  bf16x8 bgh[4][4], bgl[4][4];
  bf16x8 bch[2][4], bcl[2][4];
#pragma unroll
  for (int nt = 0; nt < 4; ++nt)
#pragma unroll
    for (int kk = 0; kk < 4; ++kk) {
      const float* base = Wg + (size_t)(128 + 32 * kk + 8 * g) * 256 + 64 * w + 16 * nt + li;
#pragma unroll
      for (int e = 0; e < 8; ++e) {
        short hi, lo;
        split_bf16(base[(size_t)e * 256], hi, lo);
        bgh[nt][kk][e] = hi; bgl[nt][kk][e] = lo;
      }
    }
#pragma unroll
  for (int ct = 0; ct < 2; ++ct)
#pragma unroll
    for (int kk = 0; kk < 4; ++kk) {
      const float* base = Wc + (size_t)(128 + 32 * kk + 8 * g) * 128 + 32 * w + 16 * ct + li;
#pragma unroll
      for (int e = 0; e < 8; ++e) {
        short hi, lo;
        split_bf16(base[(size_t)e * 128], hi, lo);
        bch[ct][kk][e] = hi; bcl[ct][kk][e] = lo;
      }
    }
  float bgj[4], bcj[2];
#pragma unroll
  for (int nt = 0; nt < 4; ++nt) bgj[nt] = bgp[64 * w + 16 * nt + li];
#pragma unroll
  for (int ct = 0; ct < 2; ++ct) bcj[ct] = bcp[32 * w + 16 * ct + li];

  if (tid < SENTS) {
    int ll = L[g0 + tid];
    len_s[tid] = ll;
    wid[0][tid] = X[(g0 + tid) * 64 + (dir ? (ll - 1) : 0)];
    wid[1][tid] = (1 < ll) ? X[(g0 + tid) * 64 + (dir ? (ll - 2) : 1)] : 0;
  }
  for (int q = tid; q < SENTS * 136; q += 256) {
    ((short*)h_hi)[q] = 0; ((short*)h_lo)[q] = 0;
  }
  for (int q = tid; q < SENTS * 132; q += 256) ((float*)h_f)[q] = 0.f;
  __syncthreads();

  int lens4[4];
#pragma unroll
  for (int r = 0; r < 4; ++r) lens4[r] = len_s[4 * g + r];
  int maxlen = 0;
#pragma unroll
  for (int m = 0; m < SENTS; ++m) maxlen = max(maxlen, len_s[m]);

  auto prefetch_x = [&](int t) {
    int b = t & 1;
#pragma unroll
    for (int c = 0; c < 6; ++c) {
      int q = tid + 256 * c;
      int m = q / 96, s = q - m * 96;
      const float* src = embProj + (size_t)wid[b][m] * 768 + dir * 384 + s * 4;
      float* dst = (float*)&xbuf[b][0][0] + q * 4;
      __builtin_amdgcn_global_load_lds(
          (const __attribute__((address_space(1))) void*)src,
          (__attribute__((address_space(3))) void*)dst, 16, 0, 0);
    }
  };

  prefetch_x(0);
  __syncthreads();

  for (int t = 0; t < maxlen; ++t) {
    const int cur = t & 1;
    prefetch_x(t + 1);
    if (tid < SENTS) {
      int ll = len_s[tid], tt = t + 2;
      wid[tt & 1][tid] = (tt < ll) ? X[(g0 + tid) * 64 + (dir ? (ll - 1 - tt) : tt)] : 0;
    }

    bf16x8 a_hi[4], a_lo[4];
#pragma unroll
    for (int kk = 0; kk < 4; ++kk) {
      a_hi[kk] = *(const bf16x8*)&h_hi[li][32 * kk + 8 * g];
      a_lo[kk] = *(const bf16x8*)&h_lo[li][32 * kk + 8 * g];
    }
    f32x4 accg[4];
#pragma unroll
    for (int nt = 0; nt < 4; ++nt) {
      const int col = 64 * w + 16 * nt + li;
      f32x4 c;
#pragma unroll
      for (int r = 0; r < 4; ++r) c[r] = bgj[nt] + xbuf[cur][4 * g + r][col];
#pragma unroll
      for (int kk = 0; kk < 4; ++kk) {
        c = __builtin_amdgcn_mfma_f32_16x16x32_bf16(a_hi[kk], bgh[nt][kk], c, 0, 0, 0);
        c = __builtin_amdgcn_mfma_f32_16x16x32_bf16(a_hi[kk], bgl[nt][kk], c, 0, 0, 0);
        c = __builtin_amdgcn_mfma_f32_16x16x32_bf16(a_lo[kk], bgh[nt][kk], c, 0, 0, 0);
      }
      accg[nt] = c;
    }
    if (w < 2) {
#pragma unroll
      for (int nt = 0; nt < 4; ++nt) {
        const int col = 64 * w + 16 * nt + li;
#pragma unroll
        for (int r = 0; r < 4; ++r) {
          const int row = 4 * g + r;
          float s = sigm(accg[nt][r]);
          float rh = s * h_f[row][col];
          short hi, lo;
          split_bf16(rh, hi, lo);
          rh_hi[row][col] = hi;
          rh_lo[row][col] = lo;
        }
      }
    } else {
#pragma unroll
      for (int nt = 0; nt < 4; ++nt) {
        const int col = 64 * (w - 2) + 16 * nt + li;
#pragma unroll
        for (int r = 0; r < 4; ++r) {
          u_f[4 * g + r][col] = sigm(accg[nt][r]);
        }
      }
    }
    __syncthreads();

    bf16x8 ra_hi[4], ra_lo[4];
#pragma unroll
    for (int kk = 0; kk < 4; ++kk) {
      ra_hi[kk] = *(const bf16x8*)&rh_hi[li][32 * kk + 8 * g];
      ra_lo[kk] = *(const bf16x8*)&rh_lo[li][32 * kk + 8 * g];
    }
#pragma unroll
    for (int ct = 0; ct < 2; ++ct) {
      const int col = 32 * w + 16 * ct + li;
      f32x4 c;
#pragma unroll
      for (int r = 0; r < 4; ++r) c[r] = bcj[ct] + xbuf[cur][4 * g + r][256 + col];
#pragma unroll
      for (int kk = 0; kk < 4; ++kk) {
        c = __builtin_amdgcn_mfma_f32_16x16x32_bf16(ra_hi[kk], bch[ct][kk], c, 0, 0, 0);
        c = __builtin_amdgcn_mfma_f32_16x16x32_bf16(ra_hi[kk], bcl[ct][kk], c, 0, 0, 0);
        c = __builtin_amdgcn_mfma_f32_16x16x32_bf16(ra_lo[kk], bch[ct][kk], c, 0, 0, 0);
      }
#pragma unroll
      for (int r = 0; r < 4; ++r) {
        const int row = 4 * g + r;
        float cand = tanh_fast(c[r]);
        float u = u_f[row][col];
        float hold = h_f[row][col];
        float hn = u * hold + (1.f - u) * cand;
        hn = (t < lens4[r]) ? hn : hold;
        h_f[row][col] = hn;
        short hi, lo;
        split_bf16(hn, hi, lo);
        h_hi[row][col] = hi;
        h_lo[row][col] = lo;
      }
    }
    __syncthreads();
  }

  for (int q = tid; q < SENTS * 128; q += 256) {
    int m = q >> 7, j = q & 127;
    size_t o = (size_t)(g0 + m) * 256 + dir * 128 + j;
    sentHi[o] = h_hi[m][j];
    sentLo[o] = h_lo[m][j];
  }
}

// ---------------------------------------------------------------------------
// Doc GRU, f16 MFMA v3. grid (4, 2), block 512 = 8 waves (2 waves/SIMD,
// 256 VGPR/thread budget). 16 docs/block. H=256.
// Wave w: gate cols [64w, 64w+64) (4 nt); cand cols [32w, 32w+32) (2 ct).
// Weights f16-hi in VGPRs: 4*8 + 2*8 = 48 frags = 192 VGPR (fits).
// A (h, rh) split f16 hi/lo, 2-pass MFMA, frags streamed 1 chunk at a time.
// ---------------------------------------------------------------------------
#define DOCS 16

__global__ __launch_bounds__(512, 1) void doc_gru_mfma(
    const float* __restrict__ xprojD, const int* __restrict__ L2,
    const float* __restrict__ dWg_f, const float* __restrict__ dbg_f,
    const float* __restrict__ dWc_f, const float* __restrict__ dbc_f,
    const float* __restrict__ dWg_b, const float* __restrict__ dbg_b,
    const float* __restrict__ dWc_b, const float* __restrict__ dbc_b,
    float* __restrict__ docv) {
  const int dir = blockIdx.y;
  const int g0 = blockIdx.x * DOCS;
  const int tid = threadIdx.x;
  const int w = tid >> 6, l = tid & 63, li = l & 15, g = l >> 4;
  const float* Wg = dir ? dWg_b : dWg_f;   // [512,512], h rows 256..511
  const float* Wc = dir ? dWc_b : dWc_f;   // [512,256]
  const float* bgp = dir ? dbg_b : dbg_f;
  const float* bcp = dir ? dbc_b : dbc_f;
  const int xoff = dir ? 768 : 0;

  alignas(16) __shared__ short h_hi[DOCS][264], h_lo[DOCS][264];
  alignas(16) __shared__ short rh_hi[DOCS][264], rh_lo[DOCS][264];
  __shared__ float h_f[DOCS][256], u_f[DOCS][256];
  __shared__ int len_s[DOCS];

  // ---- one-time: h-part weights (f16 hi plane) into VGPRs, pinned ----
  f16x8 wg[4][8];   // gates: [nt][kk], col = 64w+16nt+li, k = 32kk+8g+e
  f16x8 wc[2][8];   // cand:  [ct][kk], col = 32w+16ct+li
  const float* Wg_h = Wg + 256 * 512;
  const float* Wc_h = Wc + 256 * 256;
#pragma unroll
  for (int nt = 0; nt < 4; ++nt)
#pragma unroll
    for (int kk = 0; kk < 8; ++kk) {
      const float* base = Wg_h + (size_t)(32 * kk + 8 * g) * 512 + 64 * w + 16 * nt + li;
#pragma unroll
      for (int e = 0; e < 8; ++e) wg[nt][kk][e] = (_Float16)base[(size_t)e * 512];
      asm volatile("" : "+v"(wg[nt][kk]));
    }
#pragma unroll
  for (int ct = 0; ct < 2; ++ct)
#pragma unroll
    for (int kk = 0; kk < 8; ++kk) {
      const float* base = Wc_h + (size_t)(32 * kk + 8 * g) * 256 + 32 * w + 16 * ct + li;
#pragma unroll
      for (int e = 0; e < 8; ++e) wc[ct][kk][e] = (_Float16)base[(size_t)e * 256];
      asm volatile("" : "+v"(wc[ct][kk]));
    }
  float bgj[4], bcj[2];
#pragma unroll
  for (int nt = 0; nt < 4; ++nt) bgj[nt] = bgp[64 * w + 16 * nt + li];
#pragma unroll
  for (int ct = 0; ct < 2; ++ct) bcj[ct] = bcp[32 * w + 16 * ct + li];

  if (tid < DOCS) len_s[tid] = L2[g0 + tid];
  for (int q = tid; q < DOCS * 264; q += 512) {
    ((short*)h_hi)[q] = 0; ((short*)h_lo)[q] = 0;
  }
  for (int q = tid; q < DOCS * 256; q += 512) {
    ((float*)h_f)[q] = 0.f; ((float*)u_f)[q] = 0.f;
  }
  __syncthreads();

  int lens4[4];
#pragma unroll
  for (int r = 0; r < 4; ++r) lens4[r] = len_s[4 * g + r];
  int maxlen = 0;
#pragma unroll
  for (int m = 0; m < DOCS; ++m) maxlen = max(maxlen, len_s[m]);

  for (int t = 0; t < maxlen; ++t) {
    size_t xbase[4];
#pragma unroll
    for (int r = 0; r < 4; ++r) {
      int ti = dir ? max(lens4[r] - 1 - t, 0) : t;
      xbase[r] = ((size_t)(g0 + 4 * g + r) * 32 + ti) * 1536 + xoff;
    }

    // init gate + cand accumulators with bias + x (cand x issued early,
    // its latency hides under the gate MFMA chain)
    f32x4 acc[4];
#pragma unroll
    for (int nt = 0; nt < 4; ++nt) {
      const int col = 64 * w + 16 * nt + li;
#pragma unroll
      for (int r = 0; r < 4; ++r) acc[nt][r] = bgj[nt] + xprojD[xbase[r] + col];
    }
    f32x4 acc2[2];
#pragma unroll
    for (int ct = 0; ct < 2; ++ct) {
      const int col = 32 * w + 16 * ct + li;
#pragma unroll
      for (int r = 0; r < 4; ++r) acc2[ct][r] = bcj[ct] + xprojD[xbase[r] + 512 + col];
    }

    // ---- gates: 8 k-chunks, 2-pass (Alo*Whi + Ahi*Whi) ----
#pragma unroll
    for (int c = 0; c < 8; ++c) {
      f16x8 ah = *(const f16x8*)&h_hi[li][32 * c + 8 * g];
      f16x8 al = *(const f16x8*)&h_lo[li][32 * c + 8 * g];
#pragma unroll
      for (int nt = 0; nt < 4; ++nt) {
        acc[nt] = __builtin_amdgcn_mfma_f32_16x16x32_f16(al, wg[nt][c], acc[nt], 0, 0, 0);
        acc[nt] = __builtin_amdgcn_mfma_f32_16x16x32_f16(ah, wg[nt][c], acc[nt], 0, 0, 0);
      }
    }
    if (w < 4) {               // r-gate columns -> rh (split f16 hi/lo)
#pragma unroll
      for (int nt = 0; nt < 4; ++nt) {
        const int col = 64 * w + 16 * nt + li;
#pragma unroll
        for (int r = 0; r < 4; ++r) {
          const int m = 4 * g + r;
          float s = sigm(acc[nt][r]);
          float rh = s * h_f[m][col];
          short hi, lo;
          split_f16(rh, hi, lo);
          rh_hi[m][col] = hi;
          rh_lo[m][col] = lo;
        }
      }
    } else {                   // u-gate columns
#pragma unroll
      for (int nt = 0; nt < 4; ++nt) {
        const int col = 64 * (w - 4) + 16 * nt + li;
#pragma unroll
        for (int r = 0; r < 4; ++r) u_f[4 * g + r][col] = sigm(acc[nt][r]);
      }
    }
    __syncthreads();

    // ---- candidate: 8 k-chunks over rh ----
#pragma unroll
    for (int c = 0; c < 8; ++c) {
      f16x8 rah = *(const f16x8*)&rh_hi[li][32 * c + 8 * g];
      f16x8 ral = *(const f16x8*)&rh_lo[li][32 * c + 8 * g];
#pragma unroll
      for (int ct = 0; ct < 2; ++ct) {
        acc2[ct] = __builtin_amdgcn_mfma_f32_16x16x32_f16(ral, wc[ct][c], acc2[ct], 0, 0, 0);
        acc2[ct] = __builtin_amdgcn_mfma_f32_16x16x32_f16(rah, wc[ct][c], acc2[ct], 0, 0, 0);
      }
    }
#pragma unroll
    for (int ct = 0; ct < 2; ++ct) {
      const int col = 32 * w + 16 * ct + li;
#pragma unroll
      for (int r = 0; r < 4; ++r) {
        const int m = 4 * g + r;
        float cand = tanh_fast(acc2[ct][r]);
        float u = u_f[m][col];
        float hold = h_f[m][col];
        float hn = u * hold + (1.f - u) * cand;
        hn = (t < lens4[r]) ? hn : hold;
        h_f[m][col] = hn;
        short hi, lo;
        split_f16(hn, hi, lo);
        h_hi[m][col] = hi;
        h_lo[m][col] = lo;
      }
    }
    __syncthreads();
  }

  for (int q = tid; q < DOCS * 256; q += 512) {
    int m = q >> 8, j = q & 255;
    docv[(size_t)(g0 + m) * 512 + dir * 256 + j] = h_f[m][j];
  }
}

__global__ __launch_bounds__(256) void mlp_head(
    const float* __restrict__ docv, const float* __restrict__ W1,
    const float* __restrict__ b1, const float* __restrict__ W2,
    const float* __restrict__ b2, float* __restrict__ out) {
  const int b = blockIdx.x, j = threadIdx.x;
  __shared__ float hid[256];
  float acc = b1[j];
#pragma unroll 4
  for (int k = 0; k < 512; ++k) acc += docv[b * 512 + k] * W1[k * 256 + j];
  hid[j] = fmaxf(acc, 0.f);
  __syncthreads();
  if (j < 5) {
    float a = b2[j];
#pragma unroll 4
    for (int k = 0; k < 256; ++k) a += hid[k] * W2[k * 5 + j];
    out[b * 5 + j] = a;
  }
}

extern "C" void kernel_launch(void* const* d_in, const int* in_sizes, int n_in,
                              void* d_out, int out_size, void* d_ws, size_t ws_size,
                              hipStream_t stream) {
  const int* X = (const int*)d_in[0];
  const int* L = (const int*)d_in[1];
  const int* L2 = (const int*)d_in[2];
  const float* emb = (const float*)d_in[3];
  const float* sWg_f = (const float*)d_in[4];
  const float* sbg_f = (const float*)d_in[5];
  const float* sWc_f = (const float*)d_in[6];
  const float* sbc_f = (const float*)d_in[7];
  const float* sWg_b = (const float*)d_in[8];
  const float* sbg_b = (const float*)d_in[9];
  const float* sWc_b = (const float*)d_in[10];
  const float* sbc_b = (const float*)d_in[11];
  const float* dWg_f = (const float*)d_in[12];
  const float* dbg_f = (const float*)d_in[13];
  const float* dWc_f = (const float*)d_in[14];
  const float* dbc_f = (const float*)d_in[15];
  const float* dWg_b = (const float*)d_in[16];
  const float* dbg_b = (const float*)d_in[17];
  const float* dWc_b = (const float*)d_in[18];
  const float* dbc_b = (const float*)d_in[19];
  const float* W1 = (const float*)d_in[20];
  const float* b1 = (const float*)d_in[21];
  const float* W2 = (const float*)d_in[22];
  const float* b2 = (const float*)d_in[23];
  float* out = (float*)d_out;

  float* ws = (float*)d_ws;
  float* embProj = ws;                        // 50000*768 f32
  float* xprojD = embProj + 38400000;         // 2048*1536 f32
  float* docv = xprojD + 3145728;             // 64*512 f32
  short* sentHi = (short*)(docv + 32768);     // 2048*256 bf16
  short* sentLo = sentHi + 524288;
  short* BtHi = sentLo + 524288;              // 768*128 bf16
  short* BtLo = BtHi + 98304;
  short* PdTHi = BtLo + 98304;                // 1536*256 bf16
  short* PdTLo = PdTHi + 393216;

  // weight prep
  hipLaunchKernelGGL(bt_prep, dim3(384), dim3(256), 0, stream,
                     sWg_f, sWc_f, sWg_b, sWc_b, BtHi, BtLo);
  hipLaunchKernelGGL(packdt_prep, dim3(1536), dim3(256), 0, stream,
                     dWg_f, dWc_f, dWg_b, dWc_b, PdTHi, PdTLo);

  // embProj = emb @ packS  [50000,768] (MFMA split-bf16)
  hipLaunchKernelGGL(emb_gemm, dim3(782), dim3(256), 0, stream,
                     emb, BtHi, BtLo, embProj);

  // sentence bi-GRU -> sentHi/sentLo [2048,256] bf16 planes
  hipLaunchKernelGGL(sent_gru, dim3(128, 2), dim3(256), 0, stream,
                     X, L, embProj,
                     sWg_f, sbg_f, sWc_f, sbc_f,
                     sWg_b, sbg_b, sWc_b, sbc_b, sentHi, sentLo);

  // xprojD = sent @ packD  [2048,1536] (MFMA split-bf16)
  hipLaunchKernelGGL(xproj_gemm, dim3(32, 3), dim3(256), 0, stream,
                     sentHi, sentLo, PdTHi, PdTLo, xprojD);

  // doc bi-GRU -> docv [64,512]
  hipLaunchKernelGGL(doc_gru_mfma, dim3(4, 2), dim3(512), 0, stream,
                     xprojD, L2,
                     dWg_f, dbg_f, dWc_f, dbc_f,
                     dWg_b, dbg_b, dWc_b, dbc_b, docv);

  hipLaunchKernelGGL(mlp_head, dim3(64), dim3(256), 0, stream,
                     docv, W1, b1, W2, b2, out);
}